// Round 4
// baseline (2288.825 us; speedup 1.0000x reference)
//
#include <hip/hip_runtime.h>

#define B_  8
#define S_  4096
#define D_  512
#define P_  128
#define L_  4
#define DF_ 2048
#define DH_ 256
#define C_  2
#define MTOT (B_*S_)   // 32768
#define KC_ 8          // kv split-K chunks

typedef unsigned short u16;
typedef unsigned int   u32;
typedef short s8v __attribute__((ext_vector_type(8)));   // 8 bf16 (4 VGPRs)
typedef float f4v __attribute__((ext_vector_type(4)));

__device__ __forceinline__ float bf2f(u16 u) {
    return __uint_as_float(((u32)u) << 16);
}
__device__ __forceinline__ u16 f2bf(float f) {
    u32 x = __float_as_uint(f);
    x += 0x7fffu + ((x >> 16) & 1u);   // RNE
    return (u16)(x >> 16);
}

// fast activations: v_exp_f32 / v_rcp_f32 based (err ~1e-7 << bf16 rounding)
__device__ __forceinline__ float fast_elu1(float v) {   // elu(v)+1
    return (v > 0.f) ? (v + 1.f) : __expf(v);
}
__device__ __forceinline__ float fast_gelu(float v) {   // tanh-gelu == v*sigmoid(2u)
    float u = 0.7978845608f * (v + 0.044715f * v * v * v);
    return v * __builtin_amdgcn_rcpf(1.f + __expf(-2.f * u));
}
template<int ACT>
__device__ __forceinline__ float act_f(float v) {
    if (ACT == 1) return fast_elu1(v);
    if (ACT == 2) return fast_gelu(v);
    return v;
}

// async global->LDS, 16B per lane; LDS dest = uniform base + lane*16
__device__ __forceinline__ void gl2lds16(const u16* g, u16* l) {
    __builtin_amdgcn_global_load_lds(
        (const __attribute__((address_space(1))) u32*)g,
        (__attribute__((address_space(3))) u32*)l, 16, 0, 0);
}

#define MFMA_(d, a, bb) d = __builtin_amdgcn_mfma_f32_16x16x32_bf16(a, bb, d, 0, 0, 0)
#define SB_() __builtin_amdgcn_sched_barrier(0)

// L2-capacity-aware XCD swizzle: each XCD owns a contiguous chunk of tiles
// (bijective), and within the chunk tiles are ordered in 8(by) x SW(bx)
// supertiles, bx-major. The ~32 concurrently-resident blocks of one XCD then
// span an 8-row x 4-col window: A 2MB + B 2MB = 4MB = L2 size, instead of the
// previous 16x8 window (8MB -> thrash -> every tile re-crosses the fabric
// port at ~650GB/s/XCD, which r3 counters show is the wall).
__device__ __forceinline__ void swz_bid(int& bx, int& by) {
    const int gx = (int)gridDim.x, gy = (int)gridDim.y;
    const int nwg = gx * gy;
    if (nwg & 7) return;                 // need nwg % 8 == 0 for bijectivity
    const int id    = by * gx + bx;
    const int chunk = nwg >> 3;
    const int xcd   = id & 7;
    const int j     = id >> 3;           // sequential tile index within XCD
    const int rows  = chunk / gx;
    if ((chunk % gx) == 0 && (rows & 7) == 0) {
        const int SW   = (gx & 1) ? 1 : 2;
        const int stw  = gx / SW;        // supertiles per 8-row stripe
        const int stsz = 8 * SW;
        const int st = j / stsz, r = j % stsz;
        const int stbx = st % stw, stby = st / stw;
        by = xcd * rows + stby * 8 + (r & 7);
        bx = stbx * SW + (r >> 3);
    } else {
        const int cid = xcd * chunk + j;
        bx = cid % gx; by = cid / gx;
    }
}

// ---------------------------------------------------------------------------
// 256x256-tile, 512-thread, 3-stage-pipelined split-B bf16 GEMM:
//   C = act(A @ (Bh+Bl)^T + bias)
// Rotated schedule: per tile, G1-fragments (af0-3, b01) were prefetched at the
// END of the previous tile (right after the arrival barrier), so their LDS
// drain overlaps the previous tile's register-only C4 MFMA cluster. G2 reads
// (b23 first, then af4-7) drain under C1/C2 via counted lgkm(8/4/0).
// Single barrier per tile, placed BEFORE C4 (C4 reads registers only).
// vmcnt(6) counted: tile t+2's 6 loads stay in flight, never drained mid-loop.
// Bank-conflict-free via global-side column-slot rotation (rule #21).
// ---------------------------------------------------------------------------
template<int ACT>
__global__ __launch_bounds__(512, 2)
void gemm256_k(const u16* __restrict__ A, const u16* __restrict__ Bh,
               const u16* __restrict__ Bl, const float* __restrict__ bias,
               u16* __restrict__ C, int M, int N, int K,
               int br, int sT, long cS, int ldcT)
{
    __shared__ u16 lds[3 * 24576];
    (void)M;

    const int tid  = threadIdx.x;
    int bxs = (int)blockIdx.x, bys = (int)blockIdx.y;
    swz_bid(bxs, bys);
    const int n0   = bxs * 256;
    const int row0 = bys * 256;
    const int b    = (br > 0) ? (row0 / br) : 0;

    const int lane = tid & 63, wave = tid >> 6;
    const int quad = lane >> 4, l16 = lane & 15;
    const int wm = wave >> 2, wn = wave & 3;

    // ---- staging addressing (pre-swizzled global column slot) ----
    const int srow = lane >> 2;
    const int cswz = (((lane & 3) - ((lane >> 3) & 3)) & 3) * 8;
    const long gA0 = (long)(row0 + wave * 32 + srow) * K + cswz;
    const long gA1 = gA0 + 16 * (long)K;
    const long gB0 = (long)(n0 + wave * 32 + srow) * K + cswz;
    const long gB1 = gB0 + 16 * (long)K;

    // ---- fragment read addressing (matching swizzled slot; per-lane const) ----
    const int rq    = ((quad + ((l16 >> 1) & 3)) & 3) * 8;
    const int offA  = (wm * 128 + l16) * 32 + rq;            // + mf*512
    const int offBh = 8192  + (wn * 64 + l16) * 32 + rq;     // + nf*512
    const int offBl = 16384 + (wn * 64 + l16) * 32 + rq;

    f4v acc[8][4];
    #pragma unroll
    for (int i = 0; i < 8; i++)
        #pragma unroll
        for (int j = 0; j < 4; j++)
            acc[i][j] = (f4v){0.f, 0.f, 0.f, 0.f};

    const int NT = K >> 5;

    auto stage_tile = [&](int buf, int kof) {
        u16* d = lds + buf * 24576 + wave * 1024;
        gl2lds16(A  + gA0 + kof, d);
        gl2lds16(A  + gA1 + kof, d + 512);
        gl2lds16(Bh + gB0 + kof, d + 8192);
        gl2lds16(Bh + gB1 + kof, d + 8704);
        gl2lds16(Bl + gB0 + kof, d + 16384);
        gl2lds16(Bl + gB1 + kof, d + 16896);
    };

    // ---- prologue: tiles 0,1 in flight; wait tile 0 (counted); prefetch G1(0)
    stage_tile(0, 0);
    if (NT > 1) {
        stage_tile(1, 32);
        asm volatile("s_waitcnt vmcnt(6)" ::: "memory");
    } else {
        asm volatile("s_waitcnt vmcnt(0)" ::: "memory");
    }
    SB_();
    __builtin_amdgcn_s_barrier();
    SB_();

    s8v a03[4], b01h[2], b01l[2];               // G1 (loop-carried prefetch)
    #pragma unroll
    for (int i = 0; i < 4; i++) a03[i] = *(const s8v*)&lds[offA + i * 512];
    #pragma unroll
    for (int j = 0; j < 2; j++) {
        b01h[j] = *(const s8v*)&lds[offBh + j * 512];
        b01l[j] = *(const s8v*)&lds[offBl + j * 512];
    }

    int cb = 0;
    for (int t = 0; t < NT; ++t) {
        u16* Lc = lds + cb * 24576;
        const int  nb  = (cb + 2 >= 3) ? (cb - 1) : (cb + 2);   // (cb+2)%3
        const bool st  = (t + 2) < NT;
        const int kos = (t + 2) << 5;

        // ---- G2 reads: b23 FIRST (needed by C2 at lgkm(4)), then af4-7 ----
        s8v b23h[2], b23l[2], a47[4];
        #pragma unroll
        for (int j = 0; j < 2; j++) {
            b23h[j] = *(const s8v*)&Lc[offBh + (2 + j) * 512];
            b23l[j] = *(const s8v*)&Lc[offBl + (2 + j) * 512];
        }
        #pragma unroll
        for (int i = 0; i < 4; i++) a47[i] = *(const s8v*)&Lc[offA + (4 + i) * 512];

        // ---- stage tile t+2 into buffer nb (vmcnt only; lgkm untouched) ----
        if (st) {
            u16* Ld = lds + nb * 24576 + wave * 1024;
            gl2lds16(A  + gA0 + kos, Ld);         gl2lds16(A  + gA1 + kos, Ld + 512);
            gl2lds16(Bh + gB0 + kos, Ld + 8192);  gl2lds16(Bh + gB1 + kos, Ld + 8704);
            gl2lds16(Bl + gB0 + kos, Ld + 16384); gl2lds16(Bl + gB1 + kos, Ld + 16896);
        }

        // ---- C1: needs G1 only (8 outstanding = G2) ----
        asm volatile("s_waitcnt lgkmcnt(8)" ::: "memory");
        SB_();
        __builtin_amdgcn_s_setprio(1);
        #pragma unroll
        for (int j = 0; j < 2; j++)
            #pragma unroll
            for (int i = 0; i < 4; i++) MFMA_(acc[i][j], a03[i], b01h[j]);
        #pragma unroll
        for (int j = 0; j < 2; j++)
            #pragma unroll
            for (int i = 0; i < 4; i++) MFMA_(acc[i][j], a03[i], b01l[j]);

        // ---- C2: needs b23 (oldest 4 of G2) ----
        asm volatile("s_waitcnt lgkmcnt(4)" ::: "memory");
        SB_();
        #pragma unroll
        for (int j = 0; j < 2; j++)
            #pragma unroll
            for (int i = 0; i < 4; i++) MFMA_(acc[i][2 + j], a03[i], b23h[j]);
        #pragma unroll
        for (int j = 0; j < 2; j++)
            #pragma unroll
            for (int i = 0; i < 4; i++) MFMA_(acc[i][2 + j], a03[i], b23l[j]);

        // ---- C3: needs af4-7 ----
        asm volatile("s_waitcnt lgkmcnt(0)" ::: "memory");
        SB_();
        #pragma unroll
        for (int j = 0; j < 2; j++)
            #pragma unroll
            for (int i = 0; i < 4; i++) MFMA_(acc[4 + i][j], a47[i], b01h[j]);
        #pragma unroll
        for (int j = 0; j < 2; j++)
            #pragma unroll
            for (int i = 0; i < 4; i++) MFMA_(acc[4 + i][j], a47[i], b01l[j]);
        __builtin_amdgcn_s_setprio(0);

        // ---- arrival barrier for tile t+1, then prefetch G1(t+1); C4 (reg-only)
        // executes while G1(t+1)'s ds_reads drain. ----
        if (t + 1 < NT) {
            SB_();
            if (st) asm volatile("s_waitcnt vmcnt(6)" ::: "memory");
            else    asm volatile("s_waitcnt vmcnt(0)" ::: "memory");
            SB_();
            __builtin_amdgcn_s_barrier();
            SB_();
            const u16* Ln = lds + ((cb + 1 == 3) ? 0 : cb + 1) * 24576;
            #pragma unroll
            for (int i = 0; i < 4; i++) a03[i] = *(const s8v*)&Ln[offA + i * 512];
            #pragma unroll
            for (int j = 0; j < 2; j++) {
                b01h[j] = *(const s8v*)&Ln[offBh + j * 512];
                b01l[j] = *(const s8v*)&Ln[offBl + j * 512];
            }
            SB_();   // pin: G1(t+1) issues before C4
        }
        __builtin_amdgcn_s_setprio(1);
        #pragma unroll
        for (int j = 0; j < 2; j++)
            #pragma unroll
            for (int i = 0; i < 4; i++) MFMA_(acc[4 + i][2 + j], a47[i], b23h[j]);
        #pragma unroll
        for (int j = 0; j < 2; j++)
            #pragma unroll
            for (int i = 0; i < 4; i++) MFMA_(acc[4 + i][2 + j], a47[i], b23l[j]);
        __builtin_amdgcn_s_setprio(0);

        cb = (cb + 1 == 3) ? 0 : cb + 1;
    }

    // ---- epilogue ----
    const int sbase = (br > 0) ? (row0 % br) : row0;
    #pragma unroll
    for (int mf = 0; mf < 8; mf++) {
        #pragma unroll
        for (int nf = 0; nf < 4; nf++) {
            const int ng = n0 + wn * 64 + nf * 16 + l16;
            const float bv = bias ? bias[ng] : 0.f;
            float vals[4];
            #pragma unroll
            for (int rg = 0; rg < 4; rg++)
                vals[rg] = act_f<ACT>(acc[mf][nf][rg] + bv);
            if (sT) {
                u32 lo = (u32)f2bf(vals[0]) | ((u32)f2bf(vals[1]) << 16);
                u32 hi = (u32)f2bf(vals[2]) | ((u32)f2bf(vals[3]) << 16);
                uint2 pkd; pkd.x = lo; pkd.y = hi;
                long idx = (long)b * cS + (long)ng * ldcT + sbase + wm * 128 + mf * 16 + quad * 4;
                *(uint2*)&C[idx] = pkd;
            } else {
                #pragma unroll
                for (int rg = 0; rg < 4; rg++)
                    C[(long)(row0 + wm * 128 + mf * 16 + quad * 4 + rg) * N + ng] = f2bf(vals[rg]);
            }
        }
    }
}

// ---------------------------------------------------------------------------
// 128x128-tile bf16 MFMA GEMM (m97 structure), optional split-B:
//   C = act(A @ (Bh[+Bl])^T + bias) [* rowscale]
// (rowscale'd attn GEMM + N=128 feature-map GEMMs)
// ---------------------------------------------------------------------------
template<int ACT, int SPLITB>
__global__ __launch_bounds__(256)
void gemm128_k(const u16* __restrict__ A, const u16* __restrict__ Bh,
               const u16* __restrict__ Bl, const float* __restrict__ bias,
               const float* __restrict__ rowscale,
               u16* __restrict__ C, int M, int N, int K,
               long aS, long bS, int br, int sT, long cS, int ldcT)
{
    __shared__ u16 As [128 * 32];
    __shared__ u16 Bs [128 * 32];
    __shared__ u16 Bls[SPLITB ? 128 * 32 : 64];

    const int tid  = threadIdx.x;
    int bxs = (int)blockIdx.x, bys = (int)blockIdx.y;
    if (gridDim.z == 1) swz_bid(bxs, bys);
    const int n0   = bxs * 128;
    const int row0 = bys * 128;
    const int b    = (gridDim.z > 1) ? (int)blockIdx.z : (br > 0 ? row0 / br : 0);
    const u16* Ab  = A  + (long)b * aS;
    const u16* Bhb = Bh + (long)b * bS;
    const u16* Blb = SPLITB ? (Bl + (long)b * bS) : nullptr;

    const int lane = tid & 63, wave = tid >> 6;
    const int quad = lane >> 4, l16 = lane & 15;
    const int wm = wave >> 1, wn = wave & 1;

    const int c0 = wave * 2, c1 = wave * 2 + 1;
    const int srow = lane >> 2;          // 0..15 within chunk
    const int scol = (lane & 3) * 8;     // element col within BK=32
    const long gA0 = (long)(row0 + c0 * 16 + srow) * K + scol;
    const long gA1 = (long)(row0 + c1 * 16 + srow) * K + scol;
    const long gB0 = (long)(n0   + c0 * 16 + srow) * K + scol;
    const long gB1 = (long)(n0   + c1 * 16 + srow) * K + scol;
    u16* lA0 = &As [c0 * 512]; u16* lA1 = &As [c1 * 512];
    u16* lB0 = &Bs [c0 * 512]; u16* lB1 = &Bs [c1 * 512];
    u16* lL0 = &Bls[SPLITB ? c0 * 512 : 0];
    u16* lL1 = &Bls[SPLITB ? c1 * 512 : 0];

    f4v acc[4][4];
    #pragma unroll
    for (int i = 0; i < 4; i++)
        #pragma unroll
        for (int j = 0; j < 4; j++)
            acc[i][j] = (f4v){0.f, 0.f, 0.f, 0.f};

    for (int kt = 0; kt < K; kt += 32) {
        gl2lds16(Ab  + gA0 + kt, lA0);
        gl2lds16(Ab  + gA1 + kt, lA1);
        gl2lds16(Bhb + gB0 + kt, lB0);
        gl2lds16(Bhb + gB1 + kt, lB1);
        if (SPLITB) {
            gl2lds16(Blb + gB0 + kt, lL0);
            gl2lds16(Blb + gB1 + kt, lL1);
        }
        __syncthreads();

        s8v af[4], bh[4];
        #pragma unroll
        for (int i = 0; i < 4; i++)
            af[i] = *(const s8v*)&As[(wm * 64 + i * 16 + l16) * 32 + quad * 8];
        #pragma unroll
        for (int j = 0; j < 4; j++)
            bh[j] = *(const s8v*)&Bs[(wn * 64 + j * 16 + l16) * 32 + quad * 8];
        #pragma unroll
        for (int i = 0; i < 4; i++)
            #pragma unroll
            for (int j = 0; j < 4; j++)
                acc[i][j] = __builtin_amdgcn_mfma_f32_16x16x32_bf16(af[i], bh[j], acc[i][j], 0, 0, 0);
        if (SPLITB) {
            s8v bl[4];
            #pragma unroll
            for (int j = 0; j < 4; j++)
                bl[j] = *(const s8v*)&Bls[(wn * 64 + j * 16 + l16) * 32 + quad * 8];
            #pragma unroll
            for (int i = 0; i < 4; i++)
                #pragma unroll
                for (int j = 0; j < 4; j++)
                    acc[i][j] = __builtin_amdgcn_mfma_f32_16x16x32_bf16(af[i], bl[j], acc[i][j], 0, 0, 0);
        }
        __syncthreads();
    }

    const int sbase = (br > 0) ? (row0 % br) : row0;
    #pragma unroll
    for (int i = 0; i < 4; i++) {
        #pragma unroll
        for (int j = 0; j < 4; j++) {
            const int nl = wn * 64 + j * 16 + l16;
            const int ng = n0 + nl;
            const float bv = bias ? bias[ng] : 0.f;
            float vals[4];
            #pragma unroll
            for (int rg = 0; rg < 4; rg++) {
                const int mg = row0 + wm * 64 + i * 16 + quad * 4 + rg;
                float v = act_f<ACT>(acc[i][j][rg] + bv);
                if (rowscale) v *= rowscale[mg];
                vals[rg] = v;
            }
            if (sT) {
                u32 lo = (u32)f2bf(vals[0]) | ((u32)f2bf(vals[1]) << 16);
                u32 hi = (u32)f2bf(vals[2]) | ((u32)f2bf(vals[3]) << 16);
                uint2 pkd; pkd.x = lo; pkd.y = hi;
                long idx = (long)b * cS + (long)ng * ldcT + sbase + wm * 64 + i * 16 + quad * 4;
                *(uint2*)&C[idx] = pkd;
            } else {
                #pragma unroll
                for (int rg = 0; rg < 4; rg++) {
                    const int ml = wm * 64 + i * 16 + quad * 4 + rg;
                    C[(long)(row0 + ml) * N + ng] = f2bf(vals[rg]);
                }
            }
        }
    }
}

// ---------------------------------------------------------------------------
// kv split-K: partial[kc][b][P][D] (f32) over K-window kc*(S/KC)
// ---------------------------------------------------------------------------
__global__ __launch_bounds__(256)
void kvpart_k(const u16* __restrict__ pkT, const u16* __restrict__ vT,
              float* __restrict__ part)
{
    __shared__ u16 As[64 * 32];
    __shared__ u16 Bs[64 * 32];
    const int tid  = threadIdx.x;
    const int n0   = blockIdx.x * 64;   // D dim
    const int row0 = blockIdx.y * 64;   // P dim
    const int b    = blockIdx.z >> 3;   // KC_=8
    const int kc   = blockIdx.z & 7;
    const u16* Ab = pkT + (long)b * P_ * S_;
    const u16* Bb = vT  + (long)b * D_ * S_;

    const int lane = tid & 63, wave = tid >> 6;
    const int quad = lane >> 4, l16 = lane & 15;
    const int wm = wave >> 1, wn = wave & 1;
    const int srow = lane >> 2, scol = (lane & 3) * 8;
    const long gA = (long)(row0 + wave * 16 + srow) * S_ + scol;
    const long gB = (long)(n0   + wave * 16 + srow) * S_ + scol;
    u16* lA = &As[wave * 512];
    u16* lB = &Bs[wave * 512];

    f4v acc[2][2];
    #pragma unroll
    for (int i = 0; i < 2; i++)
        #pragma unroll
        for (int j = 0; j < 2; j++)
            acc[i][j] = (f4v){0.f, 0.f, 0.f, 0.f};

    const int k0 = kc * (S_ / KC_), k1 = k0 + S_ / KC_;
    for (int kt = k0; kt < k1; kt += 32) {
        gl2lds16(Ab + gA + kt, lA);
        gl2lds16(Bb + gB + kt, lB);
        __syncthreads();
        s8v a0 = *(const s8v*)&As[(wm * 32 + l16) * 32 + quad * 8];
        s8v a1 = *(const s8v*)&As[(wm * 32 + 16 + l16) * 32 + quad * 8];
        s8v b0 = *(const s8v*)&Bs[(wn * 32 + l16) * 32 + quad * 8];
        s8v b1 = *(const s8v*)&Bs[(wn * 32 + 16 + l16) * 32 + quad * 8];
        acc[0][0] = __builtin_amdgcn_mfma_f32_16x16x32_bf16(a0, b0, acc[0][0], 0, 0, 0);
        acc[0][1] = __builtin_amdgcn_mfma_f32_16x16x32_bf16(a0, b1, acc[0][1], 0, 0, 0);
        acc[1][0] = __builtin_amdgcn_mfma_f32_16x16x32_bf16(a1, b0, acc[1][0], 0, 0, 0);
        acc[1][1] = __builtin_amdgcn_mfma_f32_16x16x32_bf16(a1, b1, acc[1][1], 0, 0, 0);
        __syncthreads();
    }

    float* pb = part + ((long)(kc * B_ + b) * P_) * D_;
    #pragma unroll
    for (int i = 0; i < 2; i++) {
        #pragma unroll
        for (int j = 0; j < 2; j++) {
            const int ng = n0 + wn * 32 + j * 16 + l16;
            #pragma unroll
            for (int rg = 0; rg < 4; rg++) {
                const int mg = row0 + wm * 32 + i * 16 + quad * 4 + rg;
                pb[(long)mg * D_ + ng] = acc[i][j][rg];
            }
        }
    }
}

// reduce KC_ partials [P][D] -> kvT [b][D][P] bf16 (LDS 32x32 transpose)
__global__ __launch_bounds__(256)
void kvred_k(const float* __restrict__ part, u16* __restrict__ kvT)
{
    __shared__ float t[32][33];
    const int d0 = blockIdx.x * 32, p0 = blockIdx.y * 32, b = blockIdx.z;
    const int r = threadIdx.x >> 3, c4 = (threadIdx.x & 7) * 4;
    float4 s = {0.f, 0.f, 0.f, 0.f};
    #pragma unroll
    for (int kc = 0; kc < KC_; kc++) {
        const float4 v = *(const float4*)&part[(((long)(kc * B_ + b)) * P_ + p0 + r) * D_ + d0 + c4];
        s.x += v.x; s.y += v.y; s.z += v.z; s.w += v.w;
    }
    t[r][c4 + 0] = s.x; t[r][c4 + 1] = s.y; t[r][c4 + 2] = s.z; t[r][c4 + 3] = s.w;
    __syncthreads();
    u16 o[4];
    #pragma unroll
    for (int i = 0; i < 4; i++) o[i] = f2bf(t[c4 + i][r]);
    uint2 ov; ov.x = (u32)o[0] | ((u32)o[1] << 16); ov.y = (u32)o[2] | ((u32)o[3] << 16);
    *(uint2*)&kvT[(long)b * D_ * P_ + (long)(d0 + r) * P_ + p0 + c4] = ov;
}

// W [K,N] f32 -> WhT/WlT [N,K] bf16 split (w ~= hi + lo)
__global__ __launch_bounds__(256)
void tsplit_k(const float* __restrict__ W, u16* __restrict__ WhT, u16* __restrict__ WlT,
              int K, int N)
{
    __shared__ float t[32][33];
    const int n0 = blockIdx.x * 32, k0 = blockIdx.y * 32;
    const int tid = threadIdx.x;
    const int r = tid >> 3, c4 = (tid & 7) * 4;
    float4 d = *(const float4*)&W[(long)(k0 + r) * N + n0 + c4];
    t[r][c4 + 0] = d.x; t[r][c4 + 1] = d.y; t[r][c4 + 2] = d.z; t[r][c4 + 3] = d.w;
    __syncthreads();
    u16 hi[4], lo[4];
    #pragma unroll
    for (int i = 0; i < 4; i++) {
        float wv = t[c4 + i][r];
        hi[i] = f2bf(wv);
        lo[i] = f2bf(wv - bf2f(hi[i]));
    }
    uint2 hv; hv.x = (u32)hi[0] | ((u32)hi[1] << 16); hv.y = (u32)hi[2] | ((u32)hi[3] << 16);
    uint2 lv; lv.x = (u32)lo[0] | ((u32)lo[1] << 16); lv.y = (u32)lo[2] | ((u32)lo[3] << 16);
    const long oidx = (long)(n0 + r) * K + k0 + c4;
    *(uint2*)&WhT[oidx] = hv;
    *(uint2*)&WlT[oidx] = lv;
}

__global__ __launch_bounds__(256)
void embed_k(const int* __restrict__ x, const float* __restrict__ emb,
             const float* __restrict__ pos, u16* __restrict__ h)
{
    const long i8 = ((long)blockIdx.x * 256 + threadIdx.x) * 8;
    const int bs = (int)(i8 >> 9);
    const int d  = (int)(i8 & 511);
    const int tok = x[bs];
    const int sp  = bs & (S_ - 1);
    float4 e0 = *(const float4*)&emb[(long)tok * D_ + d];
    float4 e1 = *(const float4*)&emb[(long)tok * D_ + d + 4];
    float4 p0 = *(const float4*)&pos[(long)sp * D_ + d];
    float4 p1 = *(const float4*)&pos[(long)sp * D_ + d + 4];
    float4 ov; u16* ow = (u16*)&ov;
    ow[0] = f2bf(e0.x + p0.x); ow[1] = f2bf(e0.y + p0.y);
    ow[2] = f2bf(e0.z + p0.z); ow[3] = f2bf(e0.w + p0.w);
    ow[4] = f2bf(e1.x + p1.x); ow[5] = f2bf(e1.y + p1.y);
    ow[6] = f2bf(e1.z + p1.z); ow[7] = f2bf(e1.w + p1.w);
    *(float4*)&h[i8] = ov;
}

// ksum[b,p] = sum_s pkT[b,p,s]
__global__ __launch_bounds__(64)
void ksum_k(const u16* __restrict__ pkT, float* __restrict__ ks)
{
    const int bp = blockIdx.x;
    const int lane = threadIdx.x;
    const u16* row = pkT + (long)bp * S_;
    float s = 0.f;
    for (int i = lane * 8; i < S_; i += 64 * 8) {
        float4 dv = *(const float4*)&row[i];
        const u16* dw = (const u16*)&dv;
        #pragma unroll
        for (int j = 0; j < 8; j++) s += bf2f(dw[j]);
    }
    #pragma unroll
    for (int off = 32; off; off >>= 1) s += __shfl_down(s, off);
    if (lane == 0) ks[bp] = s;
}

// zinv[row] = 1 / (dot(pq[row,:], ksum[b,:]) + eps)
__global__ __launch_bounds__(256)
void zinv_k(const u16* __restrict__ pq, const float* __restrict__ ks, float* __restrict__ zi)
{
    const int row = blockIdx.x * 4 + (threadIdx.x >> 6);
    const int lane = threadIdx.x & 63;
    const u16* pr = pq + (long)row * P_;
    const float* kb = ks + (row >> 12) * P_;
    float s = bf2f(pr[lane]) * kb[lane] + bf2f(pr[lane + 64]) * kb[lane + 64];
    #pragma unroll
    for (int off = 32; off; off >>= 1) s += __shfl_down(s, off);
    if (lane == 0) zi[row] = 1.f / (s + 1e-6f);
}

// in-place LayerNorm over rows of 512 (bf16 data, f32 gains/biases)
__global__ __launch_bounds__(256)
void ln_k(u16* __restrict__ x, const float* __restrict__ g, const float* __restrict__ be)
{
    const int row = blockIdx.x * 4 + (threadIdx.x >> 6);
    const int lane = threadIdx.x & 63;
    u16* xr = x + (long)row * D_;
    float4 dv = *(const float4*)&xr[lane * 8];
    const u16* dw = (const u16*)&dv;
    float v[8], s = 0.f, s2 = 0.f;
    #pragma unroll
    for (int i = 0; i < 8; i++) { v[i] = bf2f(dw[i]); s += v[i]; s2 += v[i] * v[i]; }
    #pragma unroll
    for (int off = 32; off; off >>= 1) { s += __shfl_down(s, off); s2 += __shfl_down(s2, off); }
    s = __shfl(s, 0); s2 = __shfl(s2, 0);
    const float mu = s * (1.f / D_);
    const float var = s2 * (1.f / D_) - mu * mu;
    const float inv = rsqrtf(var + 1e-5f);
    float4 ov; u16* ow = (u16*)&ov;
    #pragma unroll
    for (int i = 0; i < 8; i++) {
        const int d = lane * 8 + i;
        ow[i] = f2bf((v[i] - mu) * inv * g[d] + be[d]);
    }
    *(float4*)&xr[lane * 8] = ov;
}

__global__ __launch_bounds__(256)
void zero_k(float* __restrict__ p, int n)
{
    const int i = blockIdx.x * 256 + threadIdx.x;
    if (i < n) p[i] = 0.f;
}

__global__ __launch_bounds__(256)
void pool_k(const u16* __restrict__ h, float* __restrict__ pooled)
{
    const int d = blockIdx.x * 256 + threadIdx.x;
    const int scnk = blockIdx.y, b = blockIdx.z;
    const u16* hb = h + (long)b * S_ * D_;
    float s = 0.f;
    for (int sr = scnk * 256; sr < scnk * 256 + 256; sr++) s += bf2f(hb[(long)sr * D_ + d]);
    atomicAdd(&pooled[b * D_ + d], s * (1.f / S_));
}

__global__ __launch_bounds__(256)
void head_k(const float* __restrict__ pooled, const float* __restrict__ Wh1, const float* __restrict__ bh1,
            const float* __restrict__ Wh2, const float* __restrict__ bh2, float* __restrict__ out)
{
    const int b = blockIdx.x, j = threadIdx.x;
    __shared__ float pl[D_];
    __shared__ float h1[DH_];
    pl[j] = pooled[b * D_ + j];
    pl[j + 256] = pooled[b * D_ + 256 + j];
    __syncthreads();
    float s = bh1[j];
    for (int d = 0; d < D_; d++) s += pl[d] * Wh1[d * DH_ + j];
    h1[j] = s > 0.f ? s : 0.f;
    __syncthreads();
    if (j < C_) {
        float o = bh2[j];
        for (int t = 0; t < DH_; t++) o += h1[t] * Wh2[t * C_ + j];
        out[b * C_ + j] = o;
    }
}

static inline void gemm256(hipStream_t st, int act,
                           const u16* A, const u16* Bh, const u16* Bl, const float* bias,
                           u16* C, int M, int N, int K, int br, int sT, long cS, int ldcT)
{
    dim3 g(N / 256, M / 256, 1), blk(512, 1, 1);
    switch (act) {
        case 0: gemm256_k<0><<<g, blk, 0, st>>>(A, Bh, Bl, bias, C, M, N, K, br, sT, cS, ldcT); break;
        case 1: gemm256_k<1><<<g, blk, 0, st>>>(A, Bh, Bl, bias, C, M, N, K, br, sT, cS, ldcT); break;
        case 2: gemm256_k<2><<<g, blk, 0, st>>>(A, Bh, Bl, bias, C, M, N, K, br, sT, cS, ldcT); break;
    }
}

static inline void gemm128(hipStream_t st, int act, int splitb,
                           const u16* A, const u16* Bh, const u16* Bl, const float* bias,
                           const float* rs, u16* C, int M, int N, int K,
                           long aS, long bS, int br, int sT, long cS, int ldcT, int gz)
{
    dim3 g(N / 128, M / 128, gz), blk(256, 1, 1);
    if (splitb) {
        switch (act) {
            case 0: gemm128_k<0,1><<<g, blk, 0, st>>>(A, Bh, Bl, bias, rs, C, M, N, K, aS, bS, br, sT, cS, ldcT); break;
            case 1: gemm128_k<1,1><<<g, blk, 0, st>>>(A, Bh, Bl, bias, rs, C, M, N, K, aS, bS, br, sT, cS, ldcT); break;
            case 2: gemm128_k<2,1><<<g, blk, 0, st>>>(A, Bh, Bl, bias, rs, C, M, N, K, aS, bS, br, sT, cS, ldcT); break;
        }
    } else {
        switch (act) {
            case 0: gemm128_k<0,0><<<g, blk, 0, st>>>(A, Bh, Bl, bias, rs, C, M, N, K, aS, bS, br, sT, cS, ldcT); break;
            case 1: gemm128_k<1,0><<<g, blk, 0, st>>>(A, Bh, Bl, bias, rs, C, M, N, K, aS, bS, br, sT, cS, ldcT); break;
            case 2: gemm128_k<2,0><<<g, blk, 0, st>>>(A, Bh, Bl, bias, rs, C, M, N, K, aS, bS, br, sT, cS, ldcT); break;
        }
    }
}

extern "C" void kernel_launch(void* const* d_in, const int* in_sizes, int n_in,
                              void* d_out, int out_size, void* d_ws, size_t ws_size,
                              hipStream_t stream)
{
    const int*   x   = (const int*)d_in[0];
    const float* emb = (const float*)d_in[1];
    const float* pos = (const float*)d_in[2];
    const float* Wq  = (const float*)d_in[3];  const float* bq  = (const float*)d_in[4];
    const float* Wk  = (const float*)d_in[5];  const float* bk  = (const float*)d_in[6];
    const float* Wv  = (const float*)d_in[7];  const float* bv  = (const float*)d_in[8];
    const float* Wf  = (const float*)d_in[9];  const float* bfb = (const float*)d_in[10];
    const float* Wo  = (const float*)d_in[11]; const float* bo  = (const float*)d_in[12];
    const float* lng = (const float*)d_in[13]; const float* lnb = (const float*)d_in[14];
    const float* W1  = (const float*)d_in[15]; const float* b1  = (const float*)d_in[16];
    const float* W2  = (const float*)d_in[17]; const float* b2  = (const float*)d_in[18];
    const float* Wh1 = (const float*)d_in[19]; const float* bh1 = (const float*)d_in[20];
    const float* Wh2 = (const float*)d_in[21]; const float* bh2 = (const float*)d_in[22];
    float* out = (float*)d_out;
    (void)in_sizes; (void)n_in; (void)out_size;

    // ---- workspace layout ----
    char* w = (char*)d_ws;
    auto alloc = [&](size_t bytes) -> char* {
        char* p = w; w += (bytes + 255) & ~(size_t)255; return p;
    };
    const size_t HBYTES = (size_t)MTOT * D_ * 2;          // 33.55 MB (bf16 activations)
    u16* h    = (u16*)alloc(HBYTES);                      // persistent hidden state
    u16* bufA = (u16*)alloc(HBYTES);                      // q / attn-out / kv partials / W splits
    u16* bufB = (u16*)alloc(HBYTES);                      // k / ln-out
    u16* wsH  = (u16*)alloc((size_t)D_ * D_ * 2);         // weight-split scratch (<= D*D)
    u16* wsL  = (u16*)alloc((size_t)D_ * D_ * 2);
    float* pooled = (float*)alloc((size_t)B_ * D_ * 4);
    // MLP hidden buffer: largest row-chunk that fits ws_size (deterministic -> graph-safe)
    size_t used = (size_t)(w - (char*)d_ws);
    int mlp_chunk = MTOT;
    while (mlp_chunk > 8192 && used + (size_t)mlp_chunk * DF_ * 2 + 4096 > ws_size)
        mlp_chunk >>= 1;
    u16* bufM = (u16*)alloc((size_t)mlp_chunk * DF_ * 2);  // MLP hidden [chunk, 2048]
    u16* bufC = bufM;                                      // vT [B,D,S] overlays bufM
    // attention temporaries overlay h (h dead between v-proj read and MLP write)
    char* hov = (char*)h;
    size_t hoff = 0;
    auto halloc = [&](size_t bytes) -> char* {
        char* p = hov + hoff; hoff += (bytes + 255) & ~(size_t)255; return p;
    };
    u16*   pq     = (u16*)  halloc((size_t)MTOT * P_ * 2);          // 8.39 MB
    u16*   pkT    = (u16*)  halloc((size_t)MTOT * P_ * 2);          // 8.39 MB
    u16*   kvT    = (u16*)  halloc((size_t)B_ * D_ * P_ * 2);       // 1.05 MB
    float* ks     = (float*)halloc((size_t)B_ * P_ * 4);
    float* zi     = (float*)halloc((size_t)MTOT * 4);
    // kv split-K partials: KC_*B*P*D f32 = 16.78 MB -> bufA (dead during attention core)
    float* kvpart = (float*)bufA;
    // W1/W2 split planes overlay bufA during the MLP (bufA dead after Wo gemm)
    u16* W1h = bufA;
    u16* W1l = bufA + (size_t)DF_ * D_;
    u16* W2h = bufA + (size_t)2 * DF_ * D_;
    u16* W2l = bufA + (size_t)3 * DF_ * D_;

    embed_k<<<(MTOT * (long)D_) / (256 * 8), 256, 0, stream>>>(x, emb, pos, h);

    for (int l = 0; l < L_; l++) {
        // q = h@Wq+bq -> bufA
        tsplit_k<<<dim3(D_ / 32, D_ / 32), 256, 0, stream>>>(Wq + (size_t)l * D_ * D_, wsH, wsL, D_, D_);
        gemm256(stream, 0, h, wsH, wsL, bq + l * D_, bufA, MTOT, D_, D_, 0, 0, 0, 0);
        // k = h@Wk+bk -> bufB
        tsplit_k<<<dim3(D_ / 32, D_ / 32), 256, 0, stream>>>(Wk + (size_t)l * D_ * D_, wsH, wsL, D_, D_);
        gemm256(stream, 0, h, wsH, wsL, bk + l * D_, bufB, MTOT, D_, D_, 0, 0, 0, 0);
        // vT = (h@Wv+bv)^T per batch -> bufC  (h's last read)
        tsplit_k<<<dim3(D_ / 32, D_ / 32), 256, 0, stream>>>(Wv + (size_t)l * D_ * D_, wsH, wsL, D_, D_);
        gemm256(stream, 0, h, wsH, wsL, bv + l * D_, bufC, MTOT, D_, D_, S_, 1, (long)D_ * S_, S_);
        // pq = elu(q@Wf+bf)+1 ; pkT = transposed per batch (128-tile, N=128 -> grid (1,256))
        tsplit_k<<<dim3(P_ / 32, D_ / 32), 256, 0, stream>>>(Wf + (size_t)l * D_ * P_, wsH, wsL, D_, P_);
        gemm128(stream, 1, 1, bufA, wsH, wsL, bfb + l * P_, nullptr, pq,  MTOT, P_, D_, 0, 0, 0,  0, 0, 0, 1);
        gemm128(stream, 1, 1, bufB, wsH, wsL, bfb + l * P_, nullptr, pkT, MTOT, P_, D_, 0, 0, S_, 1, (long)P_ * S_, S_, 1);
        // ksum, zinv
        ksum_k<<<B_ * P_, 64, 0, stream>>>(pkT, ks);
        zinv_k<<<MTOT / 4, 256, 0, stream>>>(pq, ks, zi);
        // kv split-K partials (into bufA; q already consumed) + reduce -> kvT [b][D][P]
        kvpart_k<<<dim3(D_ / 64, P_ / 64, B_ * KC_), 256, 0, stream>>>(pkT, bufC, kvpart);
        kvred_k<<<dim3(D_ / 32, P_ / 32, B_), 256, 0, stream>>>(kvpart, kvT);
        // attn = (pq @ kv) * zinv -> bufA
        gemm128(stream, 0, 0, pq, kvT, nullptr, nullptr, zi, bufA, MTOT, D_, P_, 0, (long)D_ * P_, S_, 0, 0, 0, 1);
        // o = attn@Wo+bo -> bufB, then LN in place
        tsplit_k<<<dim3(D_ / 32, D_ / 32), 256, 0, stream>>>(Wo + (size_t)l * D_ * D_, wsH, wsL, D_, D_);
        gemm256(stream, 0, bufA, wsH, wsL, bo + l * D_, bufB, MTOT, D_, D_, 0, 0, 0, 0);
        ln_k<<<MTOT / 4, 256, 0, stream>>>(bufB, lng + l * D_, lnb + l * D_);
        // MLP: W1/W2 split planes into dead bufA; row-chunks sized to workspace
        tsplit_k<<<dim3(DF_ / 32, D_ / 32), 256, 0, stream>>>(W1 + (size_t)l * D_ * DF_, W1h, W1l, D_, DF_);
        tsplit_k<<<dim3(D_ / 32, DF_ / 32), 256, 0, stream>>>(W2 + (size_t)l * DF_ * D_, W2h, W2l, DF_, D_);
        for (int c = 0; c < MTOT / mlp_chunk; c++) {
            const u16* aPtr = bufB + (size_t)c * mlp_chunk * D_;
            gemm256(stream, 2, aPtr, W1h, W1l, b1 + l * DF_, bufM, mlp_chunk, DF_, D_, 0, 0, 0, 0);
            gemm256(stream, 0, bufM, W2h, W2l, b2 + l * D_,  h + (size_t)c * mlp_chunk * D_, mlp_chunk, D_, DF_, 0, 0, 0, 0);
        }
    }

    zero_k<<<(B_ * D_ + 255) / 256, 256, 0, stream>>>(pooled, B_ * D_);
    pool_k<<<dim3(D_ / 256, 16, B_), 256, 0, stream>>>(h, pooled);
    head_k<<<B_, 256, 0, stream>>>(pooled, Wh1, bh1, Wh2, bh2, out);
}

// Round 5
// 1971.876 us; speedup vs baseline: 1.1607x; 1.1607x over previous
//
#include <hip/hip_runtime.h>

#define B_  8
#define S_  4096
#define D_  512
#define P_  128
#define L_  4
#define DF_ 2048
#define DH_ 256
#define C_  2
#define MTOT (B_*S_)   // 32768
#define KC_ 8          // kv split-K chunks

typedef unsigned short u16;
typedef unsigned int   u32;
typedef short s8v __attribute__((ext_vector_type(8)));   // 8 bf16 (4 VGPRs)
typedef float f4v __attribute__((ext_vector_type(4)));

__device__ __forceinline__ float bf2f(u16 u) {
    return __uint_as_float(((u32)u) << 16);
}
__device__ __forceinline__ u16 f2bf(float f) {
    u32 x = __float_as_uint(f);
    x += 0x7fffu + ((x >> 16) & 1u);   // RNE
    return (u16)(x >> 16);
}

// fast activations: v_exp_f32 / v_rcp_f32 based (err ~1e-7 << bf16 rounding)
__device__ __forceinline__ float fast_elu1(float v) {   // elu(v)+1
    return (v > 0.f) ? (v + 1.f) : __expf(v);
}
__device__ __forceinline__ float fast_gelu(float v) {   // tanh-gelu == v*sigmoid(2u)
    float u = 0.7978845608f * (v + 0.044715f * v * v * v);
    return v * __builtin_amdgcn_rcpf(1.f + __expf(-2.f * u));
}
template<int ACT>
__device__ __forceinline__ float act_f(float v) {
    if (ACT == 1) return fast_elu1(v);
    if (ACT == 2) return fast_gelu(v);
    return v;
}

// async global->LDS, 16B per lane; LDS dest = uniform base + lane*16
__device__ __forceinline__ void gl2lds16(const u16* g, u16* l) {
    __builtin_amdgcn_global_load_lds(
        (const __attribute__((address_space(1))) u32*)g,
        (__attribute__((address_space(3))) u32*)l, 16, 0, 0);
}

#define MFMA_(d, a, bb) d = __builtin_amdgcn_mfma_f32_16x16x32_bf16(a, bb, d, 0, 0, 0)
#define SB_() __builtin_amdgcn_sched_barrier(0)

// bijective XCD-chunk swizzle (T1), r3 form: each XCD owns a contiguous chunk
// of linear tile ids (row-major). r4's supertile variant scattered C-writes
// (WRITE_SIZE 132->185MB) and regressed; this form measured best.
__device__ __forceinline__ void swz_bid(int& bx, int& by) {
    const int gx = (int)gridDim.x, gy = (int)gridDim.y;
    const int nwg = gx * gy;
    if (nwg & 7) return;
    int id = by * gx + bx;
    id = (id & 7) * (nwg >> 3) + (id >> 3);
    bx = id % gx; by = id / gx;
}

// ---------------------------------------------------------------------------
// 256x256-tile, 512-thread, 3-stage-pipelined bf16 GEMM, optional split-B:
//   C = act(A @ (Bh[+Bl])^T + bias)
// SPLITB=1: 48KB/tile (A+Bh+Bl), 144KB LDS, 64 MFMA/wave/tile.
// SPLITB=0: 32KB/tile (A+Bh),    96KB LDS,  32 MFMA/wave/tile.
// Rotated schedule: G1 fragments prefetched at end of previous tile (overlap
// C4); G2 drains under C1/C2 via counted lgkm; single barrier per tile;
// counted vmcnt (tile t+2's loads never drained mid-loop).
// Bank-conflict-free via global-side column-slot rotation (rule #21).
// ---------------------------------------------------------------------------
template<int ACT, int SPLITB>
__global__ __launch_bounds__(512, 2)
void gemm256_k(const u16* __restrict__ A, const u16* __restrict__ Bh,
               const u16* __restrict__ Bl, const float* __restrict__ bias,
               u16* __restrict__ C, int M, int N, int K,
               int br, int sT, long cS, int ldcT)
{
    constexpr int BUF   = SPLITB ? 24576 : 16384;   // u16 per pipeline stage
    constexpr int NLD   = SPLITB ? 6 : 4;           // gl2lds per tile per wave
    __shared__ u16 lds[3 * BUF];
    (void)M;

    const int tid  = threadIdx.x;
    int bxs = (int)blockIdx.x, bys = (int)blockIdx.y;
    swz_bid(bxs, bys);
    const int n0   = bxs * 256;
    const int row0 = bys * 256;
    const int b    = (br > 0) ? (row0 / br) : 0;

    const int lane = tid & 63, wave = tid >> 6;
    const int quad = lane >> 4, l16 = lane & 15;
    const int wm = wave >> 2, wn = wave & 3;

    // ---- staging addressing (pre-swizzled global column slot) ----
    const int srow = lane >> 2;
    const int cswz = (((lane & 3) - ((lane >> 3) & 3)) & 3) * 8;
    const long gA0 = (long)(row0 + wave * 32 + srow) * K + cswz;
    const long gA1 = gA0 + 16 * (long)K;
    const long gB0 = (long)(n0 + wave * 32 + srow) * K + cswz;
    const long gB1 = gB0 + 16 * (long)K;

    // ---- fragment read addressing (matching swizzled slot; per-lane const) ----
    const int rq    = ((quad + ((l16 >> 1) & 3)) & 3) * 8;
    const int offA  = (wm * 128 + l16) * 32 + rq;            // + mf*512
    const int offBh = 8192  + (wn * 64 + l16) * 32 + rq;     // + nf*512
    const int offBl = SPLITB ? (16384 + (wn * 64 + l16) * 32 + rq) : 0;

    f4v acc[8][4];
    #pragma unroll
    for (int i = 0; i < 8; i++)
        #pragma unroll
        for (int j = 0; j < 4; j++)
            acc[i][j] = (f4v){0.f, 0.f, 0.f, 0.f};

    const int NT = K >> 5;

    auto stage_tile = [&](int buf, int kof) {
        u16* d = lds + buf * BUF + wave * 1024;
        gl2lds16(A  + gA0 + kof, d);
        gl2lds16(A  + gA1 + kof, d + 512);
        gl2lds16(Bh + gB0 + kof, d + 8192);
        gl2lds16(Bh + gB1 + kof, d + 8704);
        if (SPLITB) {
            gl2lds16(Bl + gB0 + kof, d + 16384);
            gl2lds16(Bl + gB1 + kof, d + 16896);
        }
    };

    // ---- prologue: tiles 0,1 in flight; wait tile 0 (counted); prefetch G1(0)
    stage_tile(0, 0);
    if (NT > 1) {
        stage_tile(1, 32);
        if (SPLITB) asm volatile("s_waitcnt vmcnt(6)" ::: "memory");
        else        asm volatile("s_waitcnt vmcnt(4)" ::: "memory");
    } else {
        asm volatile("s_waitcnt vmcnt(0)" ::: "memory");
    }
    SB_();
    __builtin_amdgcn_s_barrier();
    SB_();

    s8v a03[4], b01h[2], b01l[2];               // G1 (loop-carried prefetch)
    #pragma unroll
    for (int i = 0; i < 4; i++) a03[i] = *(const s8v*)&lds[offA + i * 512];
    #pragma unroll
    for (int j = 0; j < 2; j++) {
        b01h[j] = *(const s8v*)&lds[offBh + j * 512];
        if (SPLITB) b01l[j] = *(const s8v*)&lds[offBl + j * 512];
    }

    int cb = 0;
    for (int t = 0; t < NT; ++t) {
        u16* Lc = lds + cb * BUF;
        const int  nb  = (cb + 2 >= 3) ? (cb - 1) : (cb + 2);   // (cb+2)%3
        const bool st  = (t + 2) < NT;
        const int kos = (t + 2) << 5;

        // ---- G2 reads: b23 FIRST (needed by C2), then af4-7 ----
        s8v b23h[2], b23l[2], a47[4];
        #pragma unroll
        for (int j = 0; j < 2; j++) {
            b23h[j] = *(const s8v*)&Lc[offBh + (2 + j) * 512];
            if (SPLITB) b23l[j] = *(const s8v*)&Lc[offBl + (2 + j) * 512];
        }
        #pragma unroll
        for (int i = 0; i < 4; i++) a47[i] = *(const s8v*)&Lc[offA + (4 + i) * 512];

        // ---- stage tile t+2 into buffer nb (vmcnt only; lgkm untouched) ----
        if (st) stage_tile(nb, kos);

        // ---- C1: needs G1 only (G2 outstanding: 8 or 6) ----
        if (SPLITB) asm volatile("s_waitcnt lgkmcnt(8)" ::: "memory");
        else        asm volatile("s_waitcnt lgkmcnt(6)" ::: "memory");
        SB_();
        __builtin_amdgcn_s_setprio(1);
        #pragma unroll
        for (int j = 0; j < 2; j++)
            #pragma unroll
            for (int i = 0; i < 4; i++) MFMA_(acc[i][j], a03[i], b01h[j]);
        if (SPLITB) {
            #pragma unroll
            for (int j = 0; j < 2; j++)
                #pragma unroll
                for (int i = 0; i < 4; i++) MFMA_(acc[i][j], a03[i], b01l[j]);
        }

        // ---- C2: needs b23 (a47's 4 reads still outstanding) ----
        asm volatile("s_waitcnt lgkmcnt(4)" ::: "memory");
        SB_();
        #pragma unroll
        for (int j = 0; j < 2; j++)
            #pragma unroll
            for (int i = 0; i < 4; i++) MFMA_(acc[i][2 + j], a03[i], b23h[j]);
        if (SPLITB) {
            #pragma unroll
            for (int j = 0; j < 2; j++)
                #pragma unroll
                for (int i = 0; i < 4; i++) MFMA_(acc[i][2 + j], a03[i], b23l[j]);
        }

        // ---- C3: needs af4-7 ----
        asm volatile("s_waitcnt lgkmcnt(0)" ::: "memory");
        SB_();
        #pragma unroll
        for (int j = 0; j < 2; j++)
            #pragma unroll
            for (int i = 0; i < 4; i++) MFMA_(acc[4 + i][j], a47[i], b01h[j]);
        if (SPLITB) {
            #pragma unroll
            for (int j = 0; j < 2; j++)
                #pragma unroll
                for (int i = 0; i < 4; i++) MFMA_(acc[4 + i][j], a47[i], b01l[j]);
        }
        __builtin_amdgcn_s_setprio(0);

        // ---- arrival barrier for tile t+1, then prefetch G1(t+1); C4 (reg-only)
        // executes while G1(t+1)'s ds_reads drain. ----
        if (t + 1 < NT) {
            SB_();
            if (st) {
                if (SPLITB) asm volatile("s_waitcnt vmcnt(6)" ::: "memory");
                else        asm volatile("s_waitcnt vmcnt(4)" ::: "memory");
            } else {
                asm volatile("s_waitcnt vmcnt(0)" ::: "memory");
            }
            SB_();
            __builtin_amdgcn_s_barrier();
            SB_();
            const u16* Ln = lds + ((cb + 1 == 3) ? 0 : cb + 1) * BUF;
            #pragma unroll
            for (int i = 0; i < 4; i++) a03[i] = *(const s8v*)&Ln[offA + i * 512];
            #pragma unroll
            for (int j = 0; j < 2; j++) {
                b01h[j] = *(const s8v*)&Ln[offBh + j * 512];
                if (SPLITB) b01l[j] = *(const s8v*)&Ln[offBl + j * 512];
            }
            SB_();   // pin: G1(t+1) issues before C4
        }
        __builtin_amdgcn_s_setprio(1);
        #pragma unroll
        for (int j = 0; j < 2; j++)
            #pragma unroll
            for (int i = 0; i < 4; i++) MFMA_(acc[4 + i][2 + j], a47[i], b23h[j]);
        if (SPLITB) {
            #pragma unroll
            for (int j = 0; j < 2; j++)
                #pragma unroll
                for (int i = 0; i < 4; i++) MFMA_(acc[4 + i][2 + j], a47[i], b23l[j]);
        }
        __builtin_amdgcn_s_setprio(0);

        cb = (cb + 1 == 3) ? 0 : cb + 1;
    }

    // ---- epilogue ----
    const int sbase = (br > 0) ? (row0 % br) : row0;
    #pragma unroll
    for (int mf = 0; mf < 8; mf++) {
        #pragma unroll
        for (int nf = 0; nf < 4; nf++) {
            const int ng = n0 + wn * 64 + nf * 16 + l16;
            const float bv = bias ? bias[ng] : 0.f;
            float vals[4];
            #pragma unroll
            for (int rg = 0; rg < 4; rg++)
                vals[rg] = act_f<ACT>(acc[mf][nf][rg] + bv);
            if (sT) {
                u32 lo = (u32)f2bf(vals[0]) | ((u32)f2bf(vals[1]) << 16);
                u32 hi = (u32)f2bf(vals[2]) | ((u32)f2bf(vals[3]) << 16);
                uint2 pkd; pkd.x = lo; pkd.y = hi;
                long idx = (long)b * cS + (long)ng * ldcT + sbase + wm * 128 + mf * 16 + quad * 4;
                *(uint2*)&C[idx] = pkd;
            } else {
                #pragma unroll
                for (int rg = 0; rg < 4; rg++)
                    C[(long)(row0 + wm * 128 + mf * 16 + quad * 4 + rg) * N + ng] = f2bf(vals[rg]);
            }
        }
    }
}

// ---------------------------------------------------------------------------
// 128x128-tile bf16 MFMA GEMM (m97 structure), optional split-B:
//   C = act(A @ (Bh[+Bl])^T + bias) [* rowscale]
// (rowscale'd attn GEMM + N=128 feature-map GEMMs)
// ---------------------------------------------------------------------------
template<int ACT, int SPLITB>
__global__ __launch_bounds__(256)
void gemm128_k(const u16* __restrict__ A, const u16* __restrict__ Bh,
               const u16* __restrict__ Bl, const float* __restrict__ bias,
               const float* __restrict__ rowscale,
               u16* __restrict__ C, int M, int N, int K,
               long aS, long bS, int br, int sT, long cS, int ldcT)
{
    __shared__ u16 As [128 * 32];
    __shared__ u16 Bs [128 * 32];
    __shared__ u16 Bls[SPLITB ? 128 * 32 : 64];

    const int tid  = threadIdx.x;
    int bxs = (int)blockIdx.x, bys = (int)blockIdx.y;
    if (gridDim.z == 1) swz_bid(bxs, bys);
    const int n0   = bxs * 128;
    const int row0 = bys * 128;
    const int b    = (gridDim.z > 1) ? (int)blockIdx.z : (br > 0 ? row0 / br : 0);
    const u16* Ab  = A  + (long)b * aS;
    const u16* Bhb = Bh + (long)b * bS;
    const u16* Blb = SPLITB ? (Bl + (long)b * bS) : nullptr;

    const int lane = tid & 63, wave = tid >> 6;
    const int quad = lane >> 4, l16 = lane & 15;
    const int wm = wave >> 1, wn = wave & 1;

    const int c0 = wave * 2, c1 = wave * 2 + 1;
    const int srow = lane >> 2;          // 0..15 within chunk
    const int scol = (lane & 3) * 8;     // element col within BK=32
    const long gA0 = (long)(row0 + c0 * 16 + srow) * K + scol;
    const long gA1 = (long)(row0 + c1 * 16 + srow) * K + scol;
    const long gB0 = (long)(n0   + c0 * 16 + srow) * K + scol;
    const long gB1 = (long)(n0   + c1 * 16 + srow) * K + scol;
    u16* lA0 = &As [c0 * 512]; u16* lA1 = &As [c1 * 512];
    u16* lB0 = &Bs [c0 * 512]; u16* lB1 = &Bs [c1 * 512];
    u16* lL0 = &Bls[SPLITB ? c0 * 512 : 0];
    u16* lL1 = &Bls[SPLITB ? c1 * 512 : 0];

    f4v acc[4][4];
    #pragma unroll
    for (int i = 0; i < 4; i++)
        #pragma unroll
        for (int j = 0; j < 4; j++)
            acc[i][j] = (f4v){0.f, 0.f, 0.f, 0.f};

    for (int kt = 0; kt < K; kt += 32) {
        gl2lds16(Ab  + gA0 + kt, lA0);
        gl2lds16(Ab  + gA1 + kt, lA1);
        gl2lds16(Bhb + gB0 + kt, lB0);
        gl2lds16(Bhb + gB1 + kt, lB1);
        if (SPLITB) {
            gl2lds16(Blb + gB0 + kt, lL0);
            gl2lds16(Blb + gB1 + kt, lL1);
        }
        __syncthreads();

        s8v af[4], bh[4];
        #pragma unroll
        for (int i = 0; i < 4; i++)
            af[i] = *(const s8v*)&As[(wm * 64 + i * 16 + l16) * 32 + quad * 8];
        #pragma unroll
        for (int j = 0; j < 4; j++)
            bh[j] = *(const s8v*)&Bs[(wn * 64 + j * 16 + l16) * 32 + quad * 8];
        #pragma unroll
        for (int i = 0; i < 4; i++)
            #pragma unroll
            for (int j = 0; j < 4; j++)
                acc[i][j] = __builtin_amdgcn_mfma_f32_16x16x32_bf16(af[i], bh[j], acc[i][j], 0, 0, 0);
        if (SPLITB) {
            s8v bl[4];
            #pragma unroll
            for (int j = 0; j < 4; j++)
                bl[j] = *(const s8v*)&Bls[(wn * 64 + j * 16 + l16) * 32 + quad * 8];
            #pragma unroll
            for (int i = 0; i < 4; i++)
                #pragma unroll
                for (int j = 0; j < 4; j++)
                    acc[i][j] = __builtin_amdgcn_mfma_f32_16x16x32_bf16(af[i], bl[j], acc[i][j], 0, 0, 0);
        }
        __syncthreads();
    }

    const int sbase = (br > 0) ? (row0 % br) : row0;
    #pragma unroll
    for (int i = 0; i < 4; i++) {
        #pragma unroll
        for (int j = 0; j < 4; j++) {
            const int nl = wn * 64 + j * 16 + l16;
            const int ng = n0 + nl;
            const float bv = bias ? bias[ng] : 0.f;
            float vals[4];
            #pragma unroll
            for (int rg = 0; rg < 4; rg++) {
                const int mg = row0 + wm * 64 + i * 16 + quad * 4 + rg;
                float v = act_f<ACT>(acc[i][j][rg] + bv);
                if (rowscale) v *= rowscale[mg];
                vals[rg] = v;
            }
            if (sT) {
                u32 lo = (u32)f2bf(vals[0]) | ((u32)f2bf(vals[1]) << 16);
                u32 hi = (u32)f2bf(vals[2]) | ((u32)f2bf(vals[3]) << 16);
                uint2 pkd; pkd.x = lo; pkd.y = hi;
                long idx = (long)b * cS + (long)ng * ldcT + sbase + wm * 64 + i * 16 + quad * 4;
                *(uint2*)&C[idx] = pkd;
            } else {
                #pragma unroll
                for (int rg = 0; rg < 4; rg++) {
                    const int ml = wm * 64 + i * 16 + quad * 4 + rg;
                    C[(long)(row0 + ml) * N + ng] = f2bf(vals[rg]);
                }
            }
        }
    }
}

// ---------------------------------------------------------------------------
// kv split-K: partial[kc][b][P][D] (f32) over K-window kc*(S/KC)
// ---------------------------------------------------------------------------
__global__ __launch_bounds__(256)
void kvpart_k(const u16* __restrict__ pkT, const u16* __restrict__ vT,
              float* __restrict__ part)
{
    __shared__ u16 As[64 * 32];
    __shared__ u16 Bs[64 * 32];
    const int tid  = threadIdx.x;
    const int n0   = blockIdx.x * 64;   // D dim
    const int row0 = blockIdx.y * 64;   // P dim
    const int b    = blockIdx.z >> 3;   // KC_=8
    const int kc   = blockIdx.z & 7;
    const u16* Ab = pkT + (long)b * P_ * S_;
    const u16* Bb = vT  + (long)b * D_ * S_;

    const int lane = tid & 63, wave = tid >> 6;
    const int quad = lane >> 4, l16 = lane & 15;
    const int wm = wave >> 1, wn = wave & 1;
    const int srow = lane >> 2, scol = (lane & 3) * 8;
    const long gA = (long)(row0 + wave * 16 + srow) * S_ + scol;
    const long gB = (long)(n0   + wave * 16 + srow) * S_ + scol;
    u16* lA = &As[wave * 512];
    u16* lB = &Bs[wave * 512];

    f4v acc[2][2];
    #pragma unroll
    for (int i = 0; i < 2; i++)
        #pragma unroll
        for (int j = 0; j < 2; j++)
            acc[i][j] = (f4v){0.f, 0.f, 0.f, 0.f};

    const int k0 = kc * (S_ / KC_), k1 = k0 + S_ / KC_;
    for (int kt = k0; kt < k1; kt += 32) {
        gl2lds16(Ab + gA + kt, lA);
        gl2lds16(Bb + gB + kt, lB);
        __syncthreads();
        s8v a0 = *(const s8v*)&As[(wm * 32 + l16) * 32 + quad * 8];
        s8v a1 = *(const s8v*)&As[(wm * 32 + 16 + l16) * 32 + quad * 8];
        s8v b0 = *(const s8v*)&Bs[(wn * 32 + l16) * 32 + quad * 8];
        s8v b1 = *(const s8v*)&Bs[(wn * 32 + 16 + l16) * 32 + quad * 8];
        acc[0][0] = __builtin_amdgcn_mfma_f32_16x16x32_bf16(a0, b0, acc[0][0], 0, 0, 0);
        acc[0][1] = __builtin_amdgcn_mfma_f32_16x16x32_bf16(a0, b1, acc[0][1], 0, 0, 0);
        acc[1][0] = __builtin_amdgcn_mfma_f32_16x16x32_bf16(a1, b0, acc[1][0], 0, 0, 0);
        acc[1][1] = __builtin_amdgcn_mfma_f32_16x16x32_bf16(a1, b1, acc[1][1], 0, 0, 0);
        __syncthreads();
    }

    float* pb = part + ((long)(kc * B_ + b) * P_) * D_;
    #pragma unroll
    for (int i = 0; i < 2; i++) {
        #pragma unroll
        for (int j = 0; j < 2; j++) {
            const int ng = n0 + wn * 32 + j * 16 + l16;
            #pragma unroll
            for (int rg = 0; rg < 4; rg++) {
                const int mg = row0 + wm * 32 + i * 16 + quad * 4 + rg;
                pb[(long)mg * D_ + ng] = acc[i][j][rg];
            }
        }
    }
}

// reduce KC_ partials [P][D] -> kvT [b][D][P] bf16 (LDS 32x32 transpose)
__global__ __launch_bounds__(256)
void kvred_k(const float* __restrict__ part, u16* __restrict__ kvT)
{
    __shared__ float t[32][33];
    const int d0 = blockIdx.x * 32, p0 = blockIdx.y * 32, b = blockIdx.z;
    const int r = threadIdx.x >> 3, c4 = (threadIdx.x & 7) * 4;
    float4 s = {0.f, 0.f, 0.f, 0.f};
    #pragma unroll
    for (int kc = 0; kc < KC_; kc++) {
        const float4 v = *(const float4*)&part[(((long)(kc * B_ + b)) * P_ + p0 + r) * D_ + d0 + c4];
        s.x += v.x; s.y += v.y; s.z += v.z; s.w += v.w;
    }
    t[r][c4 + 0] = s.x; t[r][c4 + 1] = s.y; t[r][c4 + 2] = s.z; t[r][c4 + 3] = s.w;
    __syncthreads();
    u16 o[4];
    #pragma unroll
    for (int i = 0; i < 4; i++) o[i] = f2bf(t[c4 + i][r]);
    uint2 ov; ov.x = (u32)o[0] | ((u32)o[1] << 16); ov.y = (u32)o[2] | ((u32)o[3] << 16);
    *(uint2*)&kvT[(long)b * D_ * P_ + (long)(d0 + r) * P_ + p0 + c4] = ov;
}

// W [K,N] f32 -> WhT/WlT [N,K] bf16 split (w ~= hi + lo)
__global__ __launch_bounds__(256)
void tsplit_k(const float* __restrict__ W, u16* __restrict__ WhT, u16* __restrict__ WlT,
              int K, int N)
{
    __shared__ float t[32][33];
    const int n0 = blockIdx.x * 32, k0 = blockIdx.y * 32;
    const int tid = threadIdx.x;
    const int r = tid >> 3, c4 = (tid & 7) * 4;
    float4 d = *(const float4*)&W[(long)(k0 + r) * N + n0 + c4];
    t[r][c4 + 0] = d.x; t[r][c4 + 1] = d.y; t[r][c4 + 2] = d.z; t[r][c4 + 3] = d.w;
    __syncthreads();
    u16 hi[4], lo[4];
    #pragma unroll
    for (int i = 0; i < 4; i++) {
        float wv = t[c4 + i][r];
        hi[i] = f2bf(wv);
        lo[i] = f2bf(wv - bf2f(hi[i]));
    }
    uint2 hv; hv.x = (u32)hi[0] | ((u32)hi[1] << 16); hv.y = (u32)hi[2] | ((u32)hi[3] << 16);
    uint2 lv; lv.x = (u32)lo[0] | ((u32)lo[1] << 16); lv.y = (u32)lo[2] | ((u32)lo[3] << 16);
    const long oidx = (long)(n0 + r) * K + k0 + c4;
    *(uint2*)&WhT[oidx] = hv;
    *(uint2*)&WlT[oidx] = lv;
}

__global__ __launch_bounds__(256)
void embed_k(const int* __restrict__ x, const float* __restrict__ emb,
             const float* __restrict__ pos, u16* __restrict__ h)
{
    const long i8 = ((long)blockIdx.x * 256 + threadIdx.x) * 8;
    const int bs = (int)(i8 >> 9);
    const int d  = (int)(i8 & 511);
    const int tok = x[bs];
    const int sp  = bs & (S_ - 1);
    float4 e0 = *(const float4*)&emb[(long)tok * D_ + d];
    float4 e1 = *(const float4*)&emb[(long)tok * D_ + d + 4];
    float4 p0 = *(const float4*)&pos[(long)sp * D_ + d];
    float4 p1 = *(const float4*)&pos[(long)sp * D_ + d + 4];
    float4 ov; u16* ow = (u16*)&ov;
    ow[0] = f2bf(e0.x + p0.x); ow[1] = f2bf(e0.y + p0.y);
    ow[2] = f2bf(e0.z + p0.z); ow[3] = f2bf(e0.w + p0.w);
    ow[4] = f2bf(e1.x + p1.x); ow[5] = f2bf(e1.y + p1.y);
    ow[6] = f2bf(e1.z + p1.z); ow[7] = f2bf(e1.w + p1.w);
    *(float4*)&h[i8] = ov;
}

// ksum[b,p] = sum_s pkT[b,p,s]
__global__ __launch_bounds__(64)
void ksum_k(const u16* __restrict__ pkT, float* __restrict__ ks)
{
    const int bp = blockIdx.x;
    const int lane = threadIdx.x;
    const u16* row = pkT + (long)bp * S_;
    float s = 0.f;
    for (int i = lane * 8; i < S_; i += 64 * 8) {
        float4 dv = *(const float4*)&row[i];
        const u16* dw = (const u16*)&dv;
        #pragma unroll
        for (int j = 0; j < 8; j++) s += bf2f(dw[j]);
    }
    #pragma unroll
    for (int off = 32; off; off >>= 1) s += __shfl_down(s, off);
    if (lane == 0) ks[bp] = s;
}

// zinv[row] = 1 / (dot(pq[row,:], ksum[b,:]) + eps)
__global__ __launch_bounds__(256)
void zinv_k(const u16* __restrict__ pq, const float* __restrict__ ks, float* __restrict__ zi)
{
    const int row = blockIdx.x * 4 + (threadIdx.x >> 6);
    const int lane = threadIdx.x & 63;
    const u16* pr = pq + (long)row * P_;
    const float* kb = ks + (row >> 12) * P_;
    float s = bf2f(pr[lane]) * kb[lane] + bf2f(pr[lane + 64]) * kb[lane + 64];
    #pragma unroll
    for (int off = 32; off; off >>= 1) s += __shfl_down(s, off);
    if (lane == 0) zi[row] = 1.f / (s + 1e-6f);
}

// in-place LayerNorm over rows of 512 (bf16 data, f32 gains/biases)
__global__ __launch_bounds__(256)
void ln_k(u16* __restrict__ x, const float* __restrict__ g, const float* __restrict__ be)
{
    const int row = blockIdx.x * 4 + (threadIdx.x >> 6);
    const int lane = threadIdx.x & 63;
    u16* xr = x + (long)row * D_;
    float4 dv = *(const float4*)&xr[lane * 8];
    const u16* dw = (const u16*)&dv;
    float v[8], s = 0.f, s2 = 0.f;
    #pragma unroll
    for (int i = 0; i < 8; i++) { v[i] = bf2f(dw[i]); s += v[i]; s2 += v[i] * v[i]; }
    #pragma unroll
    for (int off = 32; off; off >>= 1) { s += __shfl_down(s, off); s2 += __shfl_down(s2, off); }
    s = __shfl(s, 0); s2 = __shfl(s2, 0);
    const float mu = s * (1.f / D_);
    const float var = s2 * (1.f / D_) - mu * mu;
    const float inv = rsqrtf(var + 1e-5f);
    float4 ov; u16* ow = (u16*)&ov;
    #pragma unroll
    for (int i = 0; i < 8; i++) {
        const int d = lane * 8 + i;
        ow[i] = f2bf((v[i] - mu) * inv * g[d] + be[d]);
    }
    *(float4*)&xr[lane * 8] = ov;
}

__global__ __launch_bounds__(256)
void zero_k(float* __restrict__ p, int n)
{
    const int i = blockIdx.x * 256 + threadIdx.x;
    if (i < n) p[i] = 0.f;
}

__global__ __launch_bounds__(256)
void pool_k(const u16* __restrict__ h, float* __restrict__ pooled)
{
    const int d = blockIdx.x * 256 + threadIdx.x;
    const int scnk = blockIdx.y, b = blockIdx.z;
    const u16* hb = h + (long)b * S_ * D_;
    float s = 0.f;
    for (int sr = scnk * 256; sr < scnk * 256 + 256; sr++) s += bf2f(hb[(long)sr * D_ + d]);
    atomicAdd(&pooled[b * D_ + d], s * (1.f / S_));
}

__global__ __launch_bounds__(256)
void head_k(const float* __restrict__ pooled, const float* __restrict__ Wh1, const float* __restrict__ bh1,
            const float* __restrict__ Wh2, const float* __restrict__ bh2, float* __restrict__ out)
{
    const int b = blockIdx.x, j = threadIdx.x;
    __shared__ float pl[D_];
    __shared__ float h1[DH_];
    pl[j] = pooled[b * D_ + j];
    pl[j + 256] = pooled[b * D_ + 256 + j];
    __syncthreads();
    float s = bh1[j];
    for (int d = 0; d < D_; d++) s += pl[d] * Wh1[d * DH_ + j];
    h1[j] = s > 0.f ? s : 0.f;
    __syncthreads();
    if (j < C_) {
        float o = bh2[j];
        for (int t = 0; t < DH_; t++) o += h1[t] * Wh2[t * C_ + j];
        out[b * C_ + j] = o;
    }
}

static inline void gemm256(hipStream_t st, int act, int splitb,
                           const u16* A, const u16* Bh, const u16* Bl, const float* bias,
                           u16* C, int M, int N, int K, int br, int sT, long cS, int ldcT)
{
    dim3 g(N / 256, M / 256, 1), blk(512, 1, 1);
    if (splitb) {
        switch (act) {
            case 0: gemm256_k<0,1><<<g, blk, 0, st>>>(A, Bh, Bl, bias, C, M, N, K, br, sT, cS, ldcT); break;
            case 1: gemm256_k<1,1><<<g, blk, 0, st>>>(A, Bh, Bl, bias, C, M, N, K, br, sT, cS, ldcT); break;
            case 2: gemm256_k<2,1><<<g, blk, 0, st>>>(A, Bh, Bl, bias, C, M, N, K, br, sT, cS, ldcT); break;
        }
    } else {
        switch (act) {
            case 0: gemm256_k<0,0><<<g, blk, 0, st>>>(A, Bh, Bl, bias, C, M, N, K, br, sT, cS, ldcT); break;
            case 1: gemm256_k<1,0><<<g, blk, 0, st>>>(A, Bh, Bl, bias, C, M, N, K, br, sT, cS, ldcT); break;
            case 2: gemm256_k<2,0><<<g, blk, 0, st>>>(A, Bh, Bl, bias, C, M, N, K, br, sT, cS, ldcT); break;
        }
    }
}

static inline void gemm128(hipStream_t st, int act, int splitb,
                           const u16* A, const u16* Bh, const u16* Bl, const float* bias,
                           const float* rs, u16* C, int M, int N, int K,
                           long aS, long bS, int br, int sT, long cS, int ldcT, int gz)
{
    dim3 g(N / 128, M / 128, gz), blk(256, 1, 1);
    if (splitb) {
        switch (act) {
            case 0: gemm128_k<0,1><<<g, blk, 0, st>>>(A, Bh, Bl, bias, rs, C, M, N, K, aS, bS, br, sT, cS, ldcT); break;
            case 1: gemm128_k<1,1><<<g, blk, 0, st>>>(A, Bh, Bl, bias, rs, C, M, N, K, aS, bS, br, sT, cS, ldcT); break;
            case 2: gemm128_k<2,1><<<g, blk, 0, st>>>(A, Bh, Bl, bias, rs, C, M, N, K, aS, bS, br, sT, cS, ldcT); break;
        }
    } else {
        switch (act) {
            case 0: gemm128_k<0,0><<<g, blk, 0, st>>>(A, Bh, Bl, bias, rs, C, M, N, K, aS, bS, br, sT, cS, ldcT); break;
            case 1: gemm128_k<1,0><<<g, blk, 0, st>>>(A, Bh, Bl, bias, rs, C, M, N, K, aS, bS, br, sT, cS, ldcT); break;
            case 2: gemm128_k<2,0><<<g, blk, 0, st>>>(A, Bh, Bl, bias, rs, C, M, N, K, aS, bS, br, sT, cS, ldcT); break;
        }
    }
}

extern "C" void kernel_launch(void* const* d_in, const int* in_sizes, int n_in,
                              void* d_out, int out_size, void* d_ws, size_t ws_size,
                              hipStream_t stream)
{
    const int*   x   = (const int*)d_in[0];
    const float* emb = (const float*)d_in[1];
    const float* pos = (const float*)d_in[2];
    const float* Wq  = (const float*)d_in[3];  const float* bq  = (const float*)d_in[4];
    const float* Wk  = (const float*)d_in[5];  const float* bk  = (const float*)d_in[6];
    const float* Wv  = (const float*)d_in[7];  const float* bv  = (const float*)d_in[8];
    const float* Wf  = (const float*)d_in[9];  const float* bfb = (const float*)d_in[10];
    const float* Wo  = (const float*)d_in[11]; const float* bo  = (const float*)d_in[12];
    const float* lng = (const float*)d_in[13]; const float* lnb = (const float*)d_in[14];
    const float* W1  = (const float*)d_in[15]; const float* b1  = (const float*)d_in[16];
    const float* W2  = (const float*)d_in[17]; const float* b2  = (const float*)d_in[18];
    const float* Wh1 = (const float*)d_in[19]; const float* bh1 = (const float*)d_in[20];
    const float* Wh2 = (const float*)d_in[21]; const float* bh2 = (const float*)d_in[22];
    float* out = (float*)d_out;
    (void)in_sizes; (void)n_in; (void)out_size;

    // ---- workspace layout ----
    char* w = (char*)d_ws;
    auto alloc = [&](size_t bytes) -> char* {
        char* p = w; w += (bytes + 255) & ~(size_t)255; return p;
    };
    const size_t HBYTES = (size_t)MTOT * D_ * 2;          // 33.55 MB (bf16 activations)
    u16* h    = (u16*)alloc(HBYTES);                      // persistent hidden state
    u16* bufA = (u16*)alloc(HBYTES);                      // q / attn-out / kv partials / W splits
    u16* bufB = (u16*)alloc(HBYTES);                      // k / ln-out
    u16* wsH  = (u16*)alloc((size_t)D_ * D_ * 2);         // weight-split scratch (<= D*D)
    u16* wsL  = (u16*)alloc((size_t)D_ * D_ * 2);
    float* pooled = (float*)alloc((size_t)B_ * D_ * 4);
    // MLP hidden buffer: largest row-chunk that fits ws_size (deterministic -> graph-safe)
    size_t used = (size_t)(w - (char*)d_ws);
    int mlp_chunk = MTOT;
    while (mlp_chunk > 8192 && used + (size_t)mlp_chunk * DF_ * 2 + 4096 > ws_size)
        mlp_chunk >>= 1;
    u16* bufM = (u16*)alloc((size_t)mlp_chunk * DF_ * 2);  // MLP hidden [chunk, 2048]
    u16* bufC = bufM;                                      // vT [B,D,S] overlays bufM
    // attention temporaries overlay h (h dead between v-proj read and MLP write)
    char* hov = (char*)h;
    size_t hoff = 0;
    auto halloc = [&](size_t bytes) -> char* {
        char* p = hov + hoff; hoff += (bytes + 255) & ~(size_t)255; return p;
    };
    u16*   pq     = (u16*)  halloc((size_t)MTOT * P_ * 2);          // 8.39 MB
    u16*   pkT    = (u16*)  halloc((size_t)MTOT * P_ * 2);          // 8.39 MB
    u16*   kvT    = (u16*)  halloc((size_t)B_ * D_ * P_ * 2);       // 1.05 MB
    float* ks     = (float*)halloc((size_t)B_ * P_ * 4);
    float* zi     = (float*)halloc((size_t)MTOT * 4);
    // kv split-K partials: KC_*B*P*D f32 = 16.78 MB -> bufA (dead during attention core)
    float* kvpart = (float*)bufA;
    // W1/W2 split planes overlay bufA during the MLP (bufA dead after Wo gemm)
    u16* W1h = bufA;
    u16* W1l = bufA + (size_t)DF_ * D_;
    u16* W2h = bufA + (size_t)2 * DF_ * D_;
    u16* W2l = bufA + (size_t)3 * DF_ * D_;

    embed_k<<<(MTOT * (long)D_) / (256 * 8), 256, 0, stream>>>(x, emb, pos, h);

    for (int l = 0; l < L_; l++) {
        // q = h@Wq+bq -> bufA
        tsplit_k<<<dim3(D_ / 32, D_ / 32), 256, 0, stream>>>(Wq + (size_t)l * D_ * D_, wsH, wsL, D_, D_);
        gemm256(stream, 0, 1, h, wsH, wsL, bq + l * D_, bufA, MTOT, D_, D_, 0, 0, 0, 0);
        // k = h@Wk+bk -> bufB
        tsplit_k<<<dim3(D_ / 32, D_ / 32), 256, 0, stream>>>(Wk + (size_t)l * D_ * D_, wsH, wsL, D_, D_);
        gemm256(stream, 0, 1, h, wsH, wsL, bk + l * D_, bufB, MTOT, D_, D_, 0, 0, 0, 0);
        // vT = (h@Wv+bv)^T per batch -> bufC  (h's last read)
        tsplit_k<<<dim3(D_ / 32, D_ / 32), 256, 0, stream>>>(Wv + (size_t)l * D_ * D_, wsH, wsL, D_, D_);
        gemm256(stream, 0, 1, h, wsH, wsL, bv + l * D_, bufC, MTOT, D_, D_, S_, 1, (long)D_ * S_, S_);
        // pq = elu(q@Wf+bf)+1 ; pkT = transposed per batch (128-tile, N=128 -> grid (1,256))
        tsplit_k<<<dim3(P_ / 32, D_ / 32), 256, 0, stream>>>(Wf + (size_t)l * D_ * P_, wsH, wsL, D_, P_);
        gemm128(stream, 1, 1, bufA, wsH, wsL, bfb + l * P_, nullptr, pq,  MTOT, P_, D_, 0, 0, 0,  0, 0, 0, 1);
        gemm128(stream, 1, 1, bufB, wsH, wsL, bfb + l * P_, nullptr, pkT, MTOT, P_, D_, 0, 0, S_, 1, (long)P_ * S_, S_, 1);
        // ksum, zinv
        ksum_k<<<B_ * P_, 64, 0, stream>>>(pkT, ks);
        zinv_k<<<MTOT / 4, 256, 0, stream>>>(pq, ks, zi);
        // kv split-K partials (into bufA; q already consumed) + reduce -> kvT [b][D][P]
        kvpart_k<<<dim3(D_ / 64, P_ / 64, B_ * KC_), 256, 0, stream>>>(pkT, bufC, kvpart);
        kvred_k<<<dim3(D_ / 32, P_ / 32, B_), 256, 0, stream>>>(kvpart, kvT);
        // attn = (pq @ kv) * zinv -> bufA
        gemm128(stream, 0, 0, pq, kvT, nullptr, nullptr, zi, bufA, MTOT, D_, P_, 0, (long)D_ * P_, S_, 0, 0, 0, 1);
        // o = attn@Wo+bo -> bufB, then LN in place
        tsplit_k<<<dim3(D_ / 32, D_ / 32), 256, 0, stream>>>(Wo + (size_t)l * D_ * D_, wsH, wsL, D_, D_);
        gemm256(stream, 0, 1, bufA, wsH, wsL, bo + l * D_, bufB, MTOT, D_, D_, 0, 0, 0, 0);
        ln_k<<<MTOT / 4, 256, 0, stream>>>(bufB, lng + l * D_, lnb + l * D_);
        // MLP: hi-plane only (lo-plane dropped: LN renorm + head mean-pool make
        // bf16 weight rounding here ~2e-3; halves MFMA + staging on 2/3 of FLOPs)
        tsplit_k<<<dim3(DF_ / 32, D_ / 32), 256, 0, stream>>>(W1 + (size_t)l * D_ * DF_, W1h, W1l, D_, DF_);
        tsplit_k<<<dim3(D_ / 32, DF_ / 32), 256, 0, stream>>>(W2 + (size_t)l * DF_ * D_, W2h, W2l, DF_, D_);
        for (int c = 0; c < MTOT / mlp_chunk; c++) {
            const u16* aPtr = bufB + (size_t)c * mlp_chunk * D_;
            gemm256(stream, 2, 0, aPtr, W1h, nullptr, b1 + l * DF_, bufM, mlp_chunk, DF_, D_, 0, 0, 0, 0);
            gemm256(stream, 0, 0, bufM, W2h, nullptr, b2 + l * D_,  h + (size_t)c * mlp_chunk * D_, mlp_chunk, D_, DF_, 0, 0, 0, 0);
        }
    }

    zero_k<<<(B_ * D_ + 255) / 256, 256, 0, stream>>>(pooled, B_ * D_);
    pool_k<<<dim3(D_ / 256, 16, B_), 256, 0, stream>>>(h, pooled);
    head_k<<<B_, 256, 0, stream>>>(pooled, Wh1, bh1, Wh2, bh2, out);
}

// Round 6
// 1929.481 us; speedup vs baseline: 1.1862x; 1.0220x over previous
//
#include <hip/hip_runtime.h>

#define B_  8
#define S_  4096
#define D_  512
#define P_  128
#define L_  4
#define DF_ 2048
#define DH_ 256
#define C_  2
#define MTOT (B_*S_)   // 32768
#define KC_ 8          // kv split-K chunks

typedef unsigned short u16;
typedef unsigned int   u32;
typedef short s8v __attribute__((ext_vector_type(8)));   // 8 bf16 (4 VGPRs)
typedef float f4v __attribute__((ext_vector_type(4)));

__device__ __forceinline__ float bf2f(u16 u) {
    return __uint_as_float(((u32)u) << 16);
}
__device__ __forceinline__ u16 f2bf(float f) {
    u32 x = __float_as_uint(f);
    x += 0x7fffu + ((x >> 16) & 1u);   // RNE
    return (u16)(x >> 16);
}

// fast activations: v_exp_f32 / v_rcp_f32 based (err ~1e-7 << bf16 rounding)
__device__ __forceinline__ float fast_elu1(float v) {   // elu(v)+1
    return (v > 0.f) ? (v + 1.f) : __expf(v);
}
__device__ __forceinline__ float fast_gelu(float v) {   // tanh-gelu == v*sigmoid(2u)
    float u = 0.7978845608f * (v + 0.044715f * v * v * v);
    return v * __builtin_amdgcn_rcpf(1.f + __expf(-2.f * u));
}
template<int ACT>
__device__ __forceinline__ float act_f(float v) {
    if (ACT == 1) return fast_elu1(v);
    if (ACT == 2) return fast_gelu(v);
    return v;
}

// async global->LDS, 16B per lane; LDS dest = uniform base + lane*16
__device__ __forceinline__ void gl2lds16(const u16* g, u16* l) {
    __builtin_amdgcn_global_load_lds(
        (const __attribute__((address_space(1))) u32*)g,
        (__attribute__((address_space(3))) u32*)l, 16, 0, 0);
}

#define MFMA_(d, a, bb) d = __builtin_amdgcn_mfma_f32_16x16x32_bf16(a, bb, d, 0, 0, 0)
#define SB_() __builtin_amdgcn_sched_barrier(0)

// bijective XCD-chunk swizzle (T1), r3 form: each XCD owns a contiguous chunk
// of linear tile ids (row-major). r4's supertile variant scattered C-writes
// (WRITE_SIZE 132->185MB) and regressed; this form measured best.
__device__ __forceinline__ void swz_bid(int& bx, int& by) {
    const int gx = (int)gridDim.x, gy = (int)gridDim.y;
    const int nwg = gx * gy;
    if (nwg & 7) return;
    int id = by * gx + bx;
    id = (id & 7) * (nwg >> 3) + (id >> 3);
    bx = id % gx; by = id / gx;
}

// ---------------------------------------------------------------------------
// Composed feature weights: WT_h/WT_l [P][D] bf16-split of (Wq @ Wf),
// bo[p] = bf[p] + sum_d bq[d]*Wf[d][p].  (q/k projections fold into the
// feature-map GEMM: no nonlinearity between Wq and Wf.)
// ---------------------------------------------------------------------------
__global__ __launch_bounds__(256)
void wcomp_k(const float* __restrict__ Wa /*[D][D]*/, const float* __restrict__ ba,
             const float* __restrict__ Wf /*[D][P]*/, const float* __restrict__ bf,
             u16* __restrict__ WTh, u16* __restrict__ WTl, float* __restrict__ bo)
{
    const int idx = blockIdx.x * 256 + threadIdx.x;   // grid 256 -> 65536
    const int p = idx & (P_ - 1);
    const int i = idx >> 7;                            // 0..511
    float s = 0.f;
    #pragma unroll 16
    for (int j = 0; j < D_; j++)
        s = fmaf(Wa[(long)i * D_ + j], Wf[(long)j * P_ + p], s);
    const u16 hi = f2bf(s);
    WTh[(long)p * D_ + i] = hi;
    WTl[(long)p * D_ + i] = f2bf(s - bf2f(hi));
    if (idx < P_) {
        float t = bf[idx];
        #pragma unroll 16
        for (int d = 0; d < D_; d++)
            t = fmaf(ba[d], Wf[(long)d * P_ + idx], t);
        bo[idx] = t;
    }
}

// ---------------------------------------------------------------------------
// 256x256-tile, 512-thread, 3-stage-pipelined bf16 GEMM, optional split-B:
//   C = act(A @ (Bh[+Bl])^T + bias)
// SPLITB=1: 48KB/tile (A+Bh+Bl), 144KB LDS, 64 MFMA/wave/tile.
// SPLITB=0: 32KB/tile (A+Bh),    96KB LDS,  32 MFMA/wave/tile.
// Rotated schedule: G1 fragments prefetched at end of previous tile (overlap
// C4); G2 drains under C1/C2 via counted lgkm; single barrier per tile;
// counted vmcnt (tile t+2's loads never drained mid-loop).
// Bank-conflict-free via global-side column-slot rotation (rule #21).
// ---------------------------------------------------------------------------
template<int ACT, int SPLITB>
__global__ __launch_bounds__(512, 2)
void gemm256_k(const u16* __restrict__ A, const u16* __restrict__ Bh,
               const u16* __restrict__ Bl, const float* __restrict__ bias,
               u16* __restrict__ C, int M, int N, int K,
               int br, int sT, long cS, int ldcT)
{
    constexpr int BUF   = SPLITB ? 24576 : 16384;   // u16 per pipeline stage
    __shared__ u16 lds[3 * BUF];
    (void)M;

    const int tid  = threadIdx.x;
    int bxs = (int)blockIdx.x, bys = (int)blockIdx.y;
    swz_bid(bxs, bys);
    const int n0   = bxs * 256;
    const int row0 = bys * 256;
    const int b    = (br > 0) ? (row0 / br) : 0;

    const int lane = tid & 63, wave = tid >> 6;
    const int quad = lane >> 4, l16 = lane & 15;
    const int wm = wave >> 2, wn = wave & 3;

    // ---- staging addressing (pre-swizzled global column slot) ----
    const int srow = lane >> 2;
    const int cswz = (((lane & 3) - ((lane >> 3) & 3)) & 3) * 8;
    const long gA0 = (long)(row0 + wave * 32 + srow) * K + cswz;
    const long gA1 = gA0 + 16 * (long)K;
    const long gB0 = (long)(n0 + wave * 32 + srow) * K + cswz;
    const long gB1 = gB0 + 16 * (long)K;

    // ---- fragment read addressing (matching swizzled slot; per-lane const) ----
    const int rq    = ((quad + ((l16 >> 1) & 3)) & 3) * 8;
    const int offA  = (wm * 128 + l16) * 32 + rq;            // + mf*512
    const int offBh = 8192  + (wn * 64 + l16) * 32 + rq;     // + nf*512
    const int offBl = SPLITB ? (16384 + (wn * 64 + l16) * 32 + rq) : 0;

    f4v acc[8][4];
    #pragma unroll
    for (int i = 0; i < 8; i++)
        #pragma unroll
        for (int j = 0; j < 4; j++)
            acc[i][j] = (f4v){0.f, 0.f, 0.f, 0.f};

    const int NT = K >> 5;

    auto stage_tile = [&](int buf, int kof) {
        u16* d = lds + buf * BUF + wave * 1024;
        gl2lds16(A  + gA0 + kof, d);
        gl2lds16(A  + gA1 + kof, d + 512);
        gl2lds16(Bh + gB0 + kof, d + 8192);
        gl2lds16(Bh + gB1 + kof, d + 8704);
        if (SPLITB) {
            gl2lds16(Bl + gB0 + kof, d + 16384);
            gl2lds16(Bl + gB1 + kof, d + 16896);
        }
    };

    // ---- prologue: tiles 0,1 in flight; wait tile 0 (counted); prefetch G1(0)
    stage_tile(0, 0);
    if (NT > 1) {
        stage_tile(1, 32);
        if (SPLITB) asm volatile("s_waitcnt vmcnt(6)" ::: "memory");
        else        asm volatile("s_waitcnt vmcnt(4)" ::: "memory");
    } else {
        asm volatile("s_waitcnt vmcnt(0)" ::: "memory");
    }
    SB_();
    __builtin_amdgcn_s_barrier();
    SB_();

    s8v a03[4], b01h[2], b01l[2];               // G1 (loop-carried prefetch)
    #pragma unroll
    for (int i = 0; i < 4; i++) a03[i] = *(const s8v*)&lds[offA + i * 512];
    #pragma unroll
    for (int j = 0; j < 2; j++) {
        b01h[j] = *(const s8v*)&lds[offBh + j * 512];
        if (SPLITB) b01l[j] = *(const s8v*)&lds[offBl + j * 512];
    }

    int cb = 0;
    for (int t = 0; t < NT; ++t) {
        u16* Lc = lds + cb * BUF;
        const int  nb  = (cb + 2 >= 3) ? (cb - 1) : (cb + 2);   // (cb+2)%3
        const bool st  = (t + 2) < NT;
        const int kos = (t + 2) << 5;

        // ---- G2 reads: b23 FIRST (needed by C2), then af4-7 ----
        s8v b23h[2], b23l[2], a47[4];
        #pragma unroll
        for (int j = 0; j < 2; j++) {
            b23h[j] = *(const s8v*)&Lc[offBh + (2 + j) * 512];
            if (SPLITB) b23l[j] = *(const s8v*)&Lc[offBl + (2 + j) * 512];
        }
        #pragma unroll
        for (int i = 0; i < 4; i++) a47[i] = *(const s8v*)&Lc[offA + (4 + i) * 512];

        // ---- stage tile t+2 into buffer nb (vmcnt only; lgkm untouched) ----
        if (st) stage_tile(nb, kos);

        // ---- C1: needs G1 only (G2 outstanding: 8 or 6) ----
        if (SPLITB) asm volatile("s_waitcnt lgkmcnt(8)" ::: "memory");
        else        asm volatile("s_waitcnt lgkmcnt(6)" ::: "memory");
        SB_();
        __builtin_amdgcn_s_setprio(1);
        #pragma unroll
        for (int j = 0; j < 2; j++)
            #pragma unroll
            for (int i = 0; i < 4; i++) MFMA_(acc[i][j], a03[i], b01h[j]);
        if (SPLITB) {
            #pragma unroll
            for (int j = 0; j < 2; j++)
                #pragma unroll
                for (int i = 0; i < 4; i++) MFMA_(acc[i][j], a03[i], b01l[j]);
        }

        // ---- C2: needs b23 (a47's 4 reads still outstanding) ----
        asm volatile("s_waitcnt lgkmcnt(4)" ::: "memory");
        SB_();
        #pragma unroll
        for (int j = 0; j < 2; j++)
            #pragma unroll
            for (int i = 0; i < 4; i++) MFMA_(acc[i][2 + j], a03[i], b23h[j]);
        if (SPLITB) {
            #pragma unroll
            for (int j = 0; j < 2; j++)
                #pragma unroll
                for (int i = 0; i < 4; i++) MFMA_(acc[i][2 + j], a03[i], b23l[j]);
        }

        // ---- C3: needs af4-7 ----
        asm volatile("s_waitcnt lgkmcnt(0)" ::: "memory");
        SB_();
        #pragma unroll
        for (int j = 0; j < 2; j++)
            #pragma unroll
            for (int i = 0; i < 4; i++) MFMA_(acc[4 + i][j], a47[i], b01h[j]);
        if (SPLITB) {
            #pragma unroll
            for (int j = 0; j < 2; j++)
                #pragma unroll
                for (int i = 0; i < 4; i++) MFMA_(acc[4 + i][j], a47[i], b01l[j]);
        }
        __builtin_amdgcn_s_setprio(0);

        // ---- arrival barrier for tile t+1, then prefetch G1(t+1); C4 (reg-only)
        // executes while G1(t+1)'s ds_reads drain. ----
        if (t + 1 < NT) {
            SB_();
            if (st) {
                if (SPLITB) asm volatile("s_waitcnt vmcnt(6)" ::: "memory");
                else        asm volatile("s_waitcnt vmcnt(4)" ::: "memory");
            } else {
                asm volatile("s_waitcnt vmcnt(0)" ::: "memory");
            }
            SB_();
            __builtin_amdgcn_s_barrier();
            SB_();
            const u16* Ln = lds + ((cb + 1 == 3) ? 0 : cb + 1) * BUF;
            #pragma unroll
            for (int i = 0; i < 4; i++) a03[i] = *(const s8v*)&Ln[offA + i * 512];
            #pragma unroll
            for (int j = 0; j < 2; j++) {
                b01h[j] = *(const s8v*)&Ln[offBh + j * 512];
                if (SPLITB) b01l[j] = *(const s8v*)&Ln[offBl + j * 512];
            }
            SB_();   // pin: G1(t+1) issues before C4
        }
        __builtin_amdgcn_s_setprio(1);
        #pragma unroll
        for (int j = 0; j < 2; j++)
            #pragma unroll
            for (int i = 0; i < 4; i++) MFMA_(acc[4 + i][2 + j], a47[i], b23h[j]);
        if (SPLITB) {
            #pragma unroll
            for (int j = 0; j < 2; j++)
                #pragma unroll
                for (int i = 0; i < 4; i++) MFMA_(acc[4 + i][2 + j], a47[i], b23l[j]);
        }
        __builtin_amdgcn_s_setprio(0);

        cb = (cb + 1 == 3) ? 0 : cb + 1;
    }

    // ---- epilogue ----
    const int sbase = (br > 0) ? (row0 % br) : row0;
    #pragma unroll
    for (int mf = 0; mf < 8; mf++) {
        #pragma unroll
        for (int nf = 0; nf < 4; nf++) {
            const int ng = n0 + wn * 64 + nf * 16 + l16;
            const float bv = bias ? bias[ng] : 0.f;
            float vals[4];
            #pragma unroll
            for (int rg = 0; rg < 4; rg++)
                vals[rg] = act_f<ACT>(acc[mf][nf][rg] + bv);
            if (sT) {
                u32 lo = (u32)f2bf(vals[0]) | ((u32)f2bf(vals[1]) << 16);
                u32 hi = (u32)f2bf(vals[2]) | ((u32)f2bf(vals[3]) << 16);
                uint2 pkd; pkd.x = lo; pkd.y = hi;
                long idx = (long)b * cS + (long)ng * ldcT + sbase + wm * 128 + mf * 16 + quad * 4;
                *(uint2*)&C[idx] = pkd;
            } else {
                #pragma unroll
                for (int rg = 0; rg < 4; rg++)
                    C[(long)(row0 + wm * 128 + mf * 16 + quad * 4 + rg) * N + ng] = f2bf(vals[rg]);
            }
        }
    }
}

// ---------------------------------------------------------------------------
// 128x128-tile bf16 MFMA GEMM (m97 structure), optional split-B:
//   C = act(A @ (Bh[+Bl])^T + bias) [* rowscale]
// (rowscale'd attn GEMM + N=128 composed feature-map GEMMs)
// ---------------------------------------------------------------------------
template<int ACT, int SPLITB>
__global__ __launch_bounds__(256)
void gemm128_k(const u16* __restrict__ A, const u16* __restrict__ Bh,
               const u16* __restrict__ Bl, const float* __restrict__ bias,
               const float* __restrict__ rowscale,
               u16* __restrict__ C, int M, int N, int K,
               long aS, long bS, int br, int sT, long cS, int ldcT)
{
    __shared__ u16 As [128 * 32];
    __shared__ u16 Bs [128 * 32];
    __shared__ u16 Bls[SPLITB ? 128 * 32 : 64];

    const int tid  = threadIdx.x;
    int bxs = (int)blockIdx.x, bys = (int)blockIdx.y;
    if (gridDim.z == 1) swz_bid(bxs, bys);
    const int n0   = bxs * 128;
    const int row0 = bys * 128;
    const int b    = (gridDim.z > 1) ? (int)blockIdx.z : (br > 0 ? row0 / br : 0);
    const u16* Ab  = A  + (long)b * aS;
    const u16* Bhb = Bh + (long)b * bS;
    const u16* Blb = SPLITB ? (Bl + (long)b * bS) : nullptr;

    const int lane = tid & 63, wave = tid >> 6;
    const int quad = lane >> 4, l16 = lane & 15;
    const int wm = wave >> 1, wn = wave & 1;

    const int c0 = wave * 2, c1 = wave * 2 + 1;
    const int srow = lane >> 2;          // 0..15 within chunk
    const int scol = (lane & 3) * 8;     // element col within BK=32
    const long gA0 = (long)(row0 + c0 * 16 + srow) * K + scol;
    const long gA1 = (long)(row0 + c1 * 16 + srow) * K + scol;
    const long gB0 = (long)(n0   + c0 * 16 + srow) * K + scol;
    const long gB1 = (long)(n0   + c1 * 16 + srow) * K + scol;
    u16* lA0 = &As [c0 * 512]; u16* lA1 = &As [c1 * 512];
    u16* lB0 = &Bs [c0 * 512]; u16* lB1 = &Bs [c1 * 512];
    u16* lL0 = &Bls[SPLITB ? c0 * 512 : 0];
    u16* lL1 = &Bls[SPLITB ? c1 * 512 : 0];

    f4v acc[4][4];
    #pragma unroll
    for (int i = 0; i < 4; i++)
        #pragma unroll
        for (int j = 0; j < 4; j++)
            acc[i][j] = (f4v){0.f, 0.f, 0.f, 0.f};

    for (int kt = 0; kt < K; kt += 32) {
        gl2lds16(Ab  + gA0 + kt, lA0);
        gl2lds16(Ab  + gA1 + kt, lA1);
        gl2lds16(Bhb + gB0 + kt, lB0);
        gl2lds16(Bhb + gB1 + kt, lB1);
        if (SPLITB) {
            gl2lds16(Blb + gB0 + kt, lL0);
            gl2lds16(Blb + gB1 + kt, lL1);
        }
        __syncthreads();

        s8v af[4], bh[4];
        #pragma unroll
        for (int i = 0; i < 4; i++)
            af[i] = *(const s8v*)&As[(wm * 64 + i * 16 + l16) * 32 + quad * 8];
        #pragma unroll
        for (int j = 0; j < 4; j++)
            bh[j] = *(const s8v*)&Bs[(wn * 64 + j * 16 + l16) * 32 + quad * 8];
        #pragma unroll
        for (int i = 0; i < 4; i++)
            #pragma unroll
            for (int j = 0; j < 4; j++)
                acc[i][j] = __builtin_amdgcn_mfma_f32_16x16x32_bf16(af[i], bh[j], acc[i][j], 0, 0, 0);
        if (SPLITB) {
            s8v bl[4];
            #pragma unroll
            for (int j = 0; j < 4; j++)
                bl[j] = *(const s8v*)&Bls[(wn * 64 + j * 16 + l16) * 32 + quad * 8];
            #pragma unroll
            for (int i = 0; i < 4; i++)
                #pragma unroll
                for (int j = 0; j < 4; j++)
                    acc[i][j] = __builtin_amdgcn_mfma_f32_16x16x32_bf16(af[i], bl[j], acc[i][j], 0, 0, 0);
        }
        __syncthreads();
    }

    const int sbase = (br > 0) ? (row0 % br) : row0;
    #pragma unroll
    for (int i = 0; i < 4; i++) {
        #pragma unroll
        for (int j = 0; j < 4; j++) {
            const int nl = wn * 64 + j * 16 + l16;
            const int ng = n0 + nl;
            const float bv = bias ? bias[ng] : 0.f;
            float vals[4];
            #pragma unroll
            for (int rg = 0; rg < 4; rg++) {
                const int mg = row0 + wm * 64 + i * 16 + quad * 4 + rg;
                float v = act_f<ACT>(acc[i][j][rg] + bv);
                if (rowscale) v *= rowscale[mg];
                vals[rg] = v;
            }
            if (sT) {
                u32 lo = (u32)f2bf(vals[0]) | ((u32)f2bf(vals[1]) << 16);
                u32 hi = (u32)f2bf(vals[2]) | ((u32)f2bf(vals[3]) << 16);
                uint2 pkd; pkd.x = lo; pkd.y = hi;
                long idx = (long)b * cS + (long)ng * ldcT + sbase + wm * 64 + i * 16 + quad * 4;
                *(uint2*)&C[idx] = pkd;
            } else {
                #pragma unroll
                for (int rg = 0; rg < 4; rg++) {
                    const int ml = wm * 64 + i * 16 + quad * 4 + rg;
                    C[(long)(row0 + ml) * N + ng] = f2bf(vals[rg]);
                }
            }
        }
    }
}

// ---------------------------------------------------------------------------
// kv split-K: partial[kc][b][P][D] (f32) over K-window kc*(S/KC)
// ---------------------------------------------------------------------------
__global__ __launch_bounds__(256)
void kvpart_k(const u16* __restrict__ pkT, const u16* __restrict__ vT,
              float* __restrict__ part)
{
    __shared__ u16 As[64 * 32];
    __shared__ u16 Bs[64 * 32];
    const int tid  = threadIdx.x;
    const int n0   = blockIdx.x * 64;   // D dim
    const int row0 = blockIdx.y * 64;   // P dim
    const int b    = blockIdx.z >> 3;   // KC_=8
    const int kc   = blockIdx.z & 7;
    const u16* Ab = pkT + (long)b * P_ * S_;
    const u16* Bb = vT  + (long)b * D_ * S_;

    const int lane = tid & 63, wave = tid >> 6;
    const int quad = lane >> 4, l16 = lane & 15;
    const int wm = wave >> 1, wn = wave & 1;
    const int srow = lane >> 2, scol = (lane & 3) * 8;
    const long gA = (long)(row0 + wave * 16 + srow) * S_ + scol;
    const long gB = (long)(n0   + wave * 16 + srow) * S_ + scol;
    u16* lA = &As[wave * 512];
    u16* lB = &Bs[wave * 512];

    f4v acc[2][2];
    #pragma unroll
    for (int i = 0; i < 2; i++)
        #pragma unroll
        for (int j = 0; j < 2; j++)
            acc[i][j] = (f4v){0.f, 0.f, 0.f, 0.f};

    const int k0 = kc * (S_ / KC_), k1 = k0 + S_ / KC_;
    for (int kt = k0; kt < k1; kt += 32) {
        gl2lds16(Ab + gA + kt, lA);
        gl2lds16(Bb + gB + kt, lB);
        __syncthreads();
        s8v a0 = *(const s8v*)&As[(wm * 32 + l16) * 32 + quad * 8];
        s8v a1 = *(const s8v*)&As[(wm * 32 + 16 + l16) * 32 + quad * 8];
        s8v b0 = *(const s8v*)&Bs[(wn * 32 + l16) * 32 + quad * 8];
        s8v b1 = *(const s8v*)&Bs[(wn * 32 + 16 + l16) * 32 + quad * 8];
        acc[0][0] = __builtin_amdgcn_mfma_f32_16x16x32_bf16(a0, b0, acc[0][0], 0, 0, 0);
        acc[0][1] = __builtin_amdgcn_mfma_f32_16x16x32_bf16(a0, b1, acc[0][1], 0, 0, 0);
        acc[1][0] = __builtin_amdgcn_mfma_f32_16x16x32_bf16(a1, b0, acc[1][0], 0, 0, 0);
        acc[1][1] = __builtin_amdgcn_mfma_f32_16x16x32_bf16(a1, b1, acc[1][1], 0, 0, 0);
        __syncthreads();
    }

    float* pb = part + ((long)(kc * B_ + b) * P_) * D_;
    #pragma unroll
    for (int i = 0; i < 2; i++) {
        #pragma unroll
        for (int j = 0; j < 2; j++) {
            const int ng = n0 + wn * 32 + j * 16 + l16;
            #pragma unroll
            for (int rg = 0; rg < 4; rg++) {
                const int mg = row0 + wm * 32 + i * 16 + quad * 4 + rg;
                pb[(long)mg * D_ + ng] = acc[i][j][rg];
            }
        }
    }
}

// reduce KC_ partials [P][D] -> kvT [b][D][P] bf16 (LDS 32x32 transpose)
__global__ __launch_bounds__(256)
void kvred_k(const float* __restrict__ part, u16* __restrict__ kvT)
{
    __shared__ float t[32][33];
    const int d0 = blockIdx.x * 32, p0 = blockIdx.y * 32, b = blockIdx.z;
    const int r = threadIdx.x >> 3, c4 = (threadIdx.x & 7) * 4;
    float4 s = {0.f, 0.f, 0.f, 0.f};
    #pragma unroll
    for (int kc = 0; kc < KC_; kc++) {
        const float4 v = *(const float4*)&part[(((long)(kc * B_ + b)) * P_ + p0 + r) * D_ + d0 + c4];
        s.x += v.x; s.y += v.y; s.z += v.z; s.w += v.w;
    }
    t[r][c4 + 0] = s.x; t[r][c4 + 1] = s.y; t[r][c4 + 2] = s.z; t[r][c4 + 3] = s.w;
    __syncthreads();
    u16 o[4];
    #pragma unroll
    for (int i = 0; i < 4; i++) o[i] = f2bf(t[c4 + i][r]);
    uint2 ov; ov.x = (u32)o[0] | ((u32)o[1] << 16); ov.y = (u32)o[2] | ((u32)o[3] << 16);
    *(uint2*)&kvT[(long)b * D_ * P_ + (long)(d0 + r) * P_ + p0 + c4] = ov;
}

// W [K,N] f32 -> WhT/WlT [N,K] bf16 split (w ~= hi + lo)
__global__ __launch_bounds__(256)
void tsplit_k(const float* __restrict__ W, u16* __restrict__ WhT, u16* __restrict__ WlT,
              int K, int N)
{
    __shared__ float t[32][33];
    const int n0 = blockIdx.x * 32, k0 = blockIdx.y * 32;
    const int tid = threadIdx.x;
    const int r = tid >> 3, c4 = (tid & 7) * 4;
    float4 d = *(const float4*)&W[(long)(k0 + r) * N + n0 + c4];
    t[r][c4 + 0] = d.x; t[r][c4 + 1] = d.y; t[r][c4 + 2] = d.z; t[r][c4 + 3] = d.w;
    __syncthreads();
    u16 hi[4], lo[4];
    #pragma unroll
    for (int i = 0; i < 4; i++) {
        float wv = t[c4 + i][r];
        hi[i] = f2bf(wv);
        lo[i] = f2bf(wv - bf2f(hi[i]));
    }
    uint2 hv; hv.x = (u32)hi[0] | ((u32)hi[1] << 16); hv.y = (u32)hi[2] | ((u32)hi[3] << 16);
    uint2 lv; lv.x = (u32)lo[0] | ((u32)lo[1] << 16); lv.y = (u32)lo[2] | ((u32)lo[3] << 16);
    const long oidx = (long)(n0 + r) * K + k0 + c4;
    *(uint2*)&WhT[oidx] = hv;
    *(uint2*)&WlT[oidx] = lv;
}

__global__ __launch_bounds__(256)
void embed_k(const int* __restrict__ x, const float* __restrict__ emb,
             const float* __restrict__ pos, u16* __restrict__ h)
{
    const long i8 = ((long)blockIdx.x * 256 + threadIdx.x) * 8;
    const int bs = (int)(i8 >> 9);
    const int d  = (int)(i8 & 511);
    const int tok = x[bs];
    const int sp  = bs & (S_ - 1);
    float4 e0 = *(const float4*)&emb[(long)tok * D_ + d];
    float4 e1 = *(const float4*)&emb[(long)tok * D_ + d + 4];
    float4 p0 = *(const float4*)&pos[(long)sp * D_ + d];
    float4 p1 = *(const float4*)&pos[(long)sp * D_ + d + 4];
    float4 ov; u16* ow = (u16*)&ov;
    ow[0] = f2bf(e0.x + p0.x); ow[1] = f2bf(e0.y + p0.y);
    ow[2] = f2bf(e0.z + p0.z); ow[3] = f2bf(e0.w + p0.w);
    ow[4] = f2bf(e1.x + p1.x); ow[5] = f2bf(e1.y + p1.y);
    ow[6] = f2bf(e1.z + p1.z); ow[7] = f2bf(e1.w + p1.w);
    *(float4*)&h[i8] = ov;
}

// ksum[b,p] = sum_s pkT[b,p,s]
__global__ __launch_bounds__(64)
void ksum_k(const u16* __restrict__ pkT, float* __restrict__ ks)
{
    const int bp = blockIdx.x;
    const int lane = threadIdx.x;
    const u16* row = pkT + (long)bp * S_;
    float s = 0.f;
    for (int i = lane * 8; i < S_; i += 64 * 8) {
        float4 dv = *(const float4*)&row[i];
        const u16* dw = (const u16*)&dv;
        #pragma unroll
        for (int j = 0; j < 8; j++) s += bf2f(dw[j]);
    }
    #pragma unroll
    for (int off = 32; off; off >>= 1) s += __shfl_down(s, off);
    if (lane == 0) ks[bp] = s;
}

// zinv[row] = 1 / (dot(pq[row,:], ksum[b,:]) + eps)
__global__ __launch_bounds__(256)
void zinv_k(const u16* __restrict__ pq, const float* __restrict__ ks, float* __restrict__ zi)
{
    const int row = blockIdx.x * 4 + (threadIdx.x >> 6);
    const int lane = threadIdx.x & 63;
    const u16* pr = pq + (long)row * P_;
    const float* kb = ks + (row >> 12) * P_;
    float s = bf2f(pr[lane]) * kb[lane] + bf2f(pr[lane + 64]) * kb[lane + 64];
    #pragma unroll
    for (int off = 32; off; off >>= 1) s += __shfl_down(s, off);
    if (lane == 0) zi[row] = 1.f / (s + 1e-6f);
}

// in-place LayerNorm over rows of 512 (bf16 data, f32 gains/biases)
__global__ __launch_bounds__(256)
void ln_k(u16* __restrict__ x, const float* __restrict__ g, const float* __restrict__ be)
{
    const int row = blockIdx.x * 4 + (threadIdx.x >> 6);
    const int lane = threadIdx.x & 63;
    u16* xr = x + (long)row * D_;
    float4 dv = *(const float4*)&xr[lane * 8];
    const u16* dw = (const u16*)&dv;
    float v[8], s = 0.f, s2 = 0.f;
    #pragma unroll
    for (int i = 0; i < 8; i++) { v[i] = bf2f(dw[i]); s += v[i]; s2 += v[i] * v[i]; }
    #pragma unroll
    for (int off = 32; off; off >>= 1) { s += __shfl_down(s, off); s2 += __shfl_down(s2, off); }
    s = __shfl(s, 0); s2 = __shfl(s2, 0);
    const float mu = s * (1.f / D_);
    const float var = s2 * (1.f / D_) - mu * mu;
    const float inv = rsqrtf(var + 1e-5f);
    float4 ov; u16* ow = (u16*)&ov;
    #pragma unroll
    for (int i = 0; i < 8; i++) {
        const int d = lane * 8 + i;
        ow[i] = f2bf((v[i] - mu) * inv * g[d] + be[d]);
    }
    *(float4*)&xr[lane * 8] = ov;
}

__global__ __launch_bounds__(256)
void zero_k(float* __restrict__ p, int n)
{
    const int i = blockIdx.x * 256 + threadIdx.x;
    if (i < n) p[i] = 0.f;
}

__global__ __launch_bounds__(256)
void pool_k(const u16* __restrict__ h, float* __restrict__ pooled)
{
    const int d = blockIdx.x * 256 + threadIdx.x;
    const int scnk = blockIdx.y, b = blockIdx.z;
    const u16* hb = h + (long)b * S_ * D_;
    float s = 0.f;
    for (int sr = scnk * 256; sr < scnk * 256 + 256; sr++) s += bf2f(hb[(long)sr * D_ + d]);
    atomicAdd(&pooled[b * D_ + d], s * (1.f / S_));
}

__global__ __launch_bounds__(256)
void head_k(const float* __restrict__ pooled, const float* __restrict__ Wh1, const float* __restrict__ bh1,
            const float* __restrict__ Wh2, const float* __restrict__ bh2, float* __restrict__ out)
{
    const int b = blockIdx.x, j = threadIdx.x;
    __shared__ float pl[D_];
    __shared__ float h1[DH_];
    pl[j] = pooled[b * D_ + j];
    pl[j + 256] = pooled[b * D_ + 256 + j];
    __syncthreads();
    float s = bh1[j];
    for (int d = 0; d < D_; d++) s += pl[d] * Wh1[d * DH_ + j];
    h1[j] = s > 0.f ? s : 0.f;
    __syncthreads();
    if (j < C_) {
        float o = bh2[j];
        for (int t = 0; t < DH_; t++) o += h1[t] * Wh2[t * C_ + j];
        out[b * C_ + j] = o;
    }
}

static inline void gemm256(hipStream_t st, int act, int splitb,
                           const u16* A, const u16* Bh, const u16* Bl, const float* bias,
                           u16* C, int M, int N, int K, int br, int sT, long cS, int ldcT)
{
    dim3 g(N / 256, M / 256, 1), blk(512, 1, 1);
    if (splitb) {
        switch (act) {
            case 0: gemm256_k<0,1><<<g, blk, 0, st>>>(A, Bh, Bl, bias, C, M, N, K, br, sT, cS, ldcT); break;
            case 1: gemm256_k<1,1><<<g, blk, 0, st>>>(A, Bh, Bl, bias, C, M, N, K, br, sT, cS, ldcT); break;
            case 2: gemm256_k<2,1><<<g, blk, 0, st>>>(A, Bh, Bl, bias, C, M, N, K, br, sT, cS, ldcT); break;
        }
    } else {
        switch (act) {
            case 0: gemm256_k<0,0><<<g, blk, 0, st>>>(A, Bh, Bl, bias, C, M, N, K, br, sT, cS, ldcT); break;
            case 1: gemm256_k<1,0><<<g, blk, 0, st>>>(A, Bh, Bl, bias, C, M, N, K, br, sT, cS, ldcT); break;
            case 2: gemm256_k<2,0><<<g, blk, 0, st>>>(A, Bh, Bl, bias, C, M, N, K, br, sT, cS, ldcT); break;
        }
    }
}

static inline void gemm128(hipStream_t st, int act, int splitb,
                           const u16* A, const u16* Bh, const u16* Bl, const float* bias,
                           const float* rs, u16* C, int M, int N, int K,
                           long aS, long bS, int br, int sT, long cS, int ldcT, int gz)
{
    dim3 g(N / 128, M / 128, gz), blk(256, 1, 1);
    if (splitb) {
        switch (act) {
            case 0: gemm128_k<0,1><<<g, blk, 0, st>>>(A, Bh, Bl, bias, rs, C, M, N, K, aS, bS, br, sT, cS, ldcT); break;
            case 1: gemm128_k<1,1><<<g, blk, 0, st>>>(A, Bh, Bl, bias, rs, C, M, N, K, aS, bS, br, sT, cS, ldcT); break;
            case 2: gemm128_k<2,1><<<g, blk, 0, st>>>(A, Bh, Bl, bias, rs, C, M, N, K, aS, bS, br, sT, cS, ldcT); break;
        }
    } else {
        switch (act) {
            case 0: gemm128_k<0,0><<<g, blk, 0, st>>>(A, Bh, Bl, bias, rs, C, M, N, K, aS, bS, br, sT, cS, ldcT); break;
            case 1: gemm128_k<1,0><<<g, blk, 0, st>>>(A, Bh, Bl, bias, rs, C, M, N, K, aS, bS, br, sT, cS, ldcT); break;
            case 2: gemm128_k<2,0><<<g, blk, 0, st>>>(A, Bh, Bl, bias, rs, C, M, N, K, aS, bS, br, sT, cS, ldcT); break;
        }
    }
}

extern "C" void kernel_launch(void* const* d_in, const int* in_sizes, int n_in,
                              void* d_out, int out_size, void* d_ws, size_t ws_size,
                              hipStream_t stream)
{
    const int*   x   = (const int*)d_in[0];
    const float* emb = (const float*)d_in[1];
    const float* pos = (const float*)d_in[2];
    const float* Wq  = (const float*)d_in[3];  const float* bq  = (const float*)d_in[4];
    const float* Wk  = (const float*)d_in[5];  const float* bk  = (const float*)d_in[6];
    const float* Wv  = (const float*)d_in[7];  const float* bv  = (const float*)d_in[8];
    const float* Wf  = (const float*)d_in[9];  const float* bfb = (const float*)d_in[10];
    const float* Wo  = (const float*)d_in[11]; const float* bo  = (const float*)d_in[12];
    const float* lng = (const float*)d_in[13]; const float* lnb = (const float*)d_in[14];
    const float* W1  = (const float*)d_in[15]; const float* b1  = (const float*)d_in[16];
    const float* W2  = (const float*)d_in[17]; const float* b2  = (const float*)d_in[18];
    const float* Wh1 = (const float*)d_in[19]; const float* bh1 = (const float*)d_in[20];
    const float* Wh2 = (const float*)d_in[21]; const float* bh2 = (const float*)d_in[22];
    float* out = (float*)d_out;
    (void)in_sizes; (void)n_in; (void)out_size;

    // ---- workspace layout ----
    char* w = (char*)d_ws;
    auto alloc = [&](size_t bytes) -> char* {
        char* p = w; w += (bytes + 255) & ~(size_t)255; return p;
    };
    const size_t HBYTES = (size_t)MTOT * D_ * 2;          // 33.55 MB (bf16 activations)
    u16* h    = (u16*)alloc(HBYTES);                      // hidden state / attn-out
    u16* bufA = (u16*)alloc(HBYTES);                      // pq + kvpart / W splits
    u16* bufB = (u16*)alloc(HBYTES);                      // pkT + kvT/ks/zi / ln-out
    u16* wsH  = (u16*)alloc((size_t)D_ * D_ * 2);         // weight-split scratch (<= D*D)
    u16* wsL  = (u16*)alloc((size_t)D_ * D_ * 2);
    float* fb = (float*)alloc((size_t)2 * P_ * 4);        // composed feature biases (q,k)
    float* pooled = (float*)alloc((size_t)B_ * D_ * 4);
    // MLP hidden buffer: largest row-chunk that fits ws_size (deterministic -> graph-safe)
    size_t used = (size_t)(w - (char*)d_ws);
    int mlp_chunk = MTOT;
    while (mlp_chunk > 8192 && used + (size_t)mlp_chunk * DF_ * 2 + 4096 > ws_size)
        mlp_chunk >>= 1;
    u16* bufM = (u16*)alloc((size_t)mlp_chunk * DF_ * 2);  // MLP hidden [chunk, 2048]
    u16* bufC = bufM;                                      // vT [B,D,S] overlays bufM (>= 33.55 MB)
    // overlays:
    u16*   pq     = bufA;                                        // 8.39 MB
    float* kvpart = (float*)(bufA + (size_t)MTOT * P_);          // 16.78 MB (8.39..25.2)
    u16*   pkT    = bufB;                                        // 8.39 MB
    u16*   kvT    = bufB + (size_t)MTOT * P_;                    // 1.05 MB
    float* ks     = (float*)(kvT + (size_t)B_ * D_ * P_);        // 4 KB
    float* zi     = ks + (size_t)B_ * P_;                        // 131 KB
    u16*   attnO  = h;                                           // h dead after v-proj
    // W1/W2 split planes overlay bufA during the MLP (pq/kvpart dead by then)
    u16* W1h = bufA;
    u16* W1l = bufA + (size_t)DF_ * D_;
    u16* W2h = bufA + (size_t)2 * DF_ * D_;
    u16* W2l = bufA + (size_t)3 * DF_ * D_;

    embed_k<<<(MTOT * (long)D_) / (256 * 8), 256, 0, stream>>>(x, emb, pos, h);

    for (int l = 0; l < L_; l++) {
        const float* Wf_l = Wf + (size_t)l * D_ * P_;
        const float* bf_l = bfb + (size_t)l * P_;
        // composed q-feature: Wqf = Wq@Wf (split planes), bqf = bq@Wf+bf
        wcomp_k<<<256, 256, 0, stream>>>(Wq + (size_t)l * D_ * D_, bq + (size_t)l * D_,
                                         Wf_l, bf_l, wsH, wsL, fb);
        // pq = elu1(h@Wqf + bqf) -> bufA
        gemm128(stream, 1, 1, h, wsH, wsL, fb, nullptr, pq, MTOT, P_, D_, 0, 0, 0, 0, 0, 0, 1);
        // composed k-feature
        wcomp_k<<<256, 256, 0, stream>>>(Wk + (size_t)l * D_ * D_, bk + (size_t)l * D_,
                                         Wf_l, bf_l, wsH, wsL, fb + P_);
        // pkT = elu1(h@Wkf + bkf)^T per batch -> bufB
        gemm128(stream, 1, 1, h, wsH, wsL, fb + P_, nullptr, pkT, MTOT, P_, D_, 0, 0, S_, 1, (long)P_ * S_, S_, 1);
        // vT = (h@Wv+bv)^T per batch -> bufC  (h's last read)
        tsplit_k<<<dim3(D_ / 32, D_ / 32), 256, 0, stream>>>(Wv + (size_t)l * D_ * D_, wsH, wsL, D_, D_);
        gemm256(stream, 0, 1, h, wsH, wsL, bv + l * D_, bufC, MTOT, D_, D_, S_, 1, (long)D_ * S_, S_);
        // ksum, zinv
        ksum_k<<<B_ * P_, 64, 0, stream>>>(pkT, ks);
        zinv_k<<<MTOT / 4, 256, 0, stream>>>(pq, ks, zi);
        // kv split-K partials + reduce -> kvT [b][D][P]
        kvpart_k<<<dim3(D_ / 64, P_ / 64, B_ * KC_), 256, 0, stream>>>(pkT, bufC, kvpart);
        kvred_k<<<dim3(D_ / 32, P_ / 32, B_), 256, 0, stream>>>(kvpart, kvT);
        // attn = (pq @ kv) * zinv -> h region (h dead)
        gemm128(stream, 0, 0, pq, kvT, nullptr, nullptr, zi, attnO, MTOT, D_, P_, 0, (long)D_ * P_, S_, 0, 0, 0, 1);
        // o = attn@Wo+bo -> bufB (pkT/kvT/zi dead), then LN in place
        tsplit_k<<<dim3(D_ / 32, D_ / 32), 256, 0, stream>>>(Wo + (size_t)l * D_ * D_, wsH, wsL, D_, D_);
        gemm256(stream, 0, 1, attnO, wsH, wsL, bo + l * D_, bufB, MTOT, D_, D_, 0, 0, 0, 0);
        ln_k<<<MTOT / 4, 256, 0, stream>>>(bufB, lng + l * D_, lnb + l * D_);
        // MLP: hi-plane only (lo dropped: LN renorm + mean-pool tolerate bf16 W here)
        tsplit_k<<<dim3(DF_ / 32, D_ / 32), 256, 0, stream>>>(W1 + (size_t)l * D_ * DF_, W1h, W1l, D_, DF_);
        tsplit_k<<<dim3(D_ / 32, DF_ / 32), 256, 0, stream>>>(W2 + (size_t)l * DF_ * D_, W2h, W2l, DF_, D_);
        for (int c = 0; c < MTOT / mlp_chunk; c++) {
            const u16* aPtr = bufB + (size_t)c * mlp_chunk * D_;
            gemm256(stream, 2, 0, aPtr, W1h, nullptr, b1 + l * DF_, bufM, mlp_chunk, DF_, D_, 0, 0, 0, 0);
            gemm256(stream, 0, 0, bufM, W2h, nullptr, b2 + l * D_,  h + (size_t)c * mlp_chunk * D_, mlp_chunk, D_, DF_, 0, 0, 0, 0);
        }
    }

    zero_k<<<(B_ * D_ + 255) / 256, 256, 0, stream>>>(pooled, B_ * D_);
    pool_k<<<dim3(D_ / 256, 16, B_), 256, 0, stream>>>(h, pooled);
    head_k<<<B_, 256, 0, stream>>>(pooled, Wh1, bh1, Wh2, bh2, out);
}

// Round 7
// 1801.880 us; speedup vs baseline: 1.2702x; 1.0708x over previous
//
#include <hip/hip_runtime.h>

#define B_  8
#define S_  4096
#define D_  512
#define P_  128
#define L_  4
#define DF_ 2048
#define DH_ 256
#define C_  2
#define MTOT (B_*S_)   // 32768
#define KC_ 8          // kv split-K chunks
#define JC_ 8          // wcomp split-K chunks

typedef unsigned short u16;
typedef unsigned int   u32;
typedef short s8v __attribute__((ext_vector_type(8)));   // 8 bf16 (4 VGPRs)
typedef float f4v __attribute__((ext_vector_type(4)));

__device__ __forceinline__ float bf2f(u16 u) {
    return __uint_as_float(((u32)u) << 16);
}
__device__ __forceinline__ u16 f2bf(float f) {
    u32 x = __float_as_uint(f);
    x += 0x7fffu + ((x >> 16) & 1u);   // RNE
    return (u16)(x >> 16);
}

// fast activations: v_exp_f32 / v_rcp_f32 based (err ~1e-7 << bf16 rounding)
__device__ __forceinline__ float fast_elu1(float v) {   // elu(v)+1
    return (v > 0.f) ? (v + 1.f) : __expf(v);
}
__device__ __forceinline__ float fast_gelu(float v) {   // tanh-gelu == v*sigmoid(2u)
    float u = 0.7978845608f * (v + 0.044715f * v * v * v);
    return v * __builtin_amdgcn_rcpf(1.f + __expf(-2.f * u));
}
template<int ACT>
__device__ __forceinline__ float act_f(float v) {
    if (ACT == 1) return fast_elu1(v);
    if (ACT == 2) return fast_gelu(v);
    return v;
}

// async global->LDS, 16B per lane; LDS dest = uniform base + lane*16
__device__ __forceinline__ void gl2lds16(const u16* g, u16* l) {
    __builtin_amdgcn_global_load_lds(
        (const __attribute__((address_space(1))) u32*)g,
        (__attribute__((address_space(3))) u32*)l, 16, 0, 0);
}

#define MFMA_(d, a, bb) d = __builtin_amdgcn_mfma_f32_16x16x32_bf16(a, bb, d, 0, 0, 0)
#define SB_() __builtin_amdgcn_sched_barrier(0)

// bijective XCD-chunk swizzle (T1), r3 form: each XCD owns a contiguous chunk
// of linear tile ids (row-major). r4's supertile variant scattered C-writes
// (WRITE_SIZE 132->185MB) and regressed; this form measured best.
__device__ __forceinline__ void swz_bid(int& bx, int& by) {
    const int gx = (int)gridDim.x, gy = (int)gridDim.y;
    const int nwg = gx * gy;
    if (nwg & 7) return;
    int id = by * gx + bx;
    id = (id & 7) * (nwg >> 3) + (id >> 3);
    bx = id % gx; by = id / gx;
}

// ---------------------------------------------------------------------------
// Composed feature weights, split-K (r6's wcomp was latency-starved: 256
// blocks x 512-long serial chains ~26us). wpart_k: 2048 blocks, JC=8 K-chunks
// of 64 FMAs -> part[jc][i][p]; block 2048 computes the composed bias.
// wfin_k: sum partials (i-fast mapping -> coalesced WTh/WTl writes), hi/lo.
// ---------------------------------------------------------------------------
__global__ __launch_bounds__(256)
void wpart_k(const float* __restrict__ Wa /*[D][D]*/, const float* __restrict__ ba,
             const float* __restrict__ Wf /*[D][P]*/, const float* __restrict__ bf,
             float* __restrict__ part, float* __restrict__ bo)
{
    const int bid = blockIdx.x;
    const int tid = threadIdx.x;
    if (bid == (D_ * P_ * JC_) / 256) {            // bias block (2048)
        __shared__ float bs[2][P_];
        const int p = tid & 127, hf = tid >> 7;
        float t = 0.f;
        for (int d = hf * 256; d < hf * 256 + 256; d++)
            t = fmaf(ba[d], Wf[(long)d * P_ + p], t);
        bs[hf][p] = t;
        __syncthreads();
        if (hf == 0) bo[p] = bs[0][p] + bs[1][p] + bf[p];
        return;
    }
    const int g  = bid * 256 + tid;
    const int p  = g & 127;                         // fast -> Wf coalesced
    const int i  = (g >> 7) & 511;                  // wave-uniform -> Wa scalar
    const int jc = g >> 16;
    float s = 0.f;
    #pragma unroll 8
    for (int j = jc * 64; j < jc * 64 + 64; j++)
        s = fmaf(Wa[(long)i * D_ + j], Wf[(long)j * P_ + p], s);
    part[((long)jc * D_ + i) * P_ + p] = s;         // p fast -> coalesced
}

__global__ __launch_bounds__(256)
void wfin_k(const float* __restrict__ part, u16* __restrict__ WTh, u16* __restrict__ WTl)
{
    const int idx = blockIdx.x * 256 + threadIdx.x; // grid 256 -> 65536
    const int i = idx & 511;                        // fast -> coalesced writes
    const int p = idx >> 9;
    float s = 0.f;
    #pragma unroll
    for (int jc = 0; jc < JC_; jc++)
        s += part[((long)jc * D_ + i) * P_ + p];
    const u16 hi = f2bf(s);
    WTh[(long)p * D_ + i] = hi;
    WTl[(long)p * D_ + i] = f2bf(s - bf2f(hi));
}

// ---------------------------------------------------------------------------
// 256x256-tile, 512-thread, 3-stage-pipelined bf16 GEMM, optional split-B:
//   C = act(A @ (Bh[+Bl])^T + bias)
// SPLITB=1: 48KB/tile (A+Bh+Bl), 144KB LDS, 64 MFMA/wave/tile.
// SPLITB=0: 32KB/tile (A+Bh),    96KB LDS,  32 MFMA/wave/tile.
// Rotated schedule: G1 fragments prefetched at end of previous tile (overlap
// C4); G2 drains under C1/C2 via counted lgkm; single barrier per tile;
// counted vmcnt (tile t+2's loads never drained mid-loop).
// Bank-conflict-free via global-side column-slot rotation (rule #21).
// ---------------------------------------------------------------------------
template<int ACT, int SPLITB>
__global__ __launch_bounds__(512, 2)
void gemm256_k(const u16* __restrict__ A, const u16* __restrict__ Bh,
               const u16* __restrict__ Bl, const float* __restrict__ bias,
               u16* __restrict__ C, int M, int N, int K,
               int br, int sT, long cS, int ldcT)
{
    constexpr int BUF   = SPLITB ? 24576 : 16384;   // u16 per pipeline stage
    __shared__ u16 lds[3 * BUF];
    (void)M;

    const int tid  = threadIdx.x;
    int bxs = (int)blockIdx.x, bys = (int)blockIdx.y;
    swz_bid(bxs, bys);
    const int n0   = bxs * 256;
    const int row0 = bys * 256;
    const int b    = (br > 0) ? (row0 / br) : 0;

    const int lane = tid & 63, wave = tid >> 6;
    const int quad = lane >> 4, l16 = lane & 15;
    const int wm = wave >> 2, wn = wave & 3;

    // ---- staging addressing (pre-swizzled global column slot) ----
    const int srow = lane >> 2;
    const int cswz = (((lane & 3) - ((lane >> 3) & 3)) & 3) * 8;
    const long gA0 = (long)(row0 + wave * 32 + srow) * K + cswz;
    const long gA1 = gA0 + 16 * (long)K;
    const long gB0 = (long)(n0 + wave * 32 + srow) * K + cswz;
    const long gB1 = gB0 + 16 * (long)K;

    // ---- fragment read addressing (matching swizzled slot; per-lane const) ----
    const int rq    = ((quad + ((l16 >> 1) & 3)) & 3) * 8;
    const int offA  = (wm * 128 + l16) * 32 + rq;            // + mf*512
    const int offBh = 8192  + (wn * 64 + l16) * 32 + rq;     // + nf*512
    const int offBl = SPLITB ? (16384 + (wn * 64 + l16) * 32 + rq) : 0;

    f4v acc[8][4];
    #pragma unroll
    for (int i = 0; i < 8; i++)
        #pragma unroll
        for (int j = 0; j < 4; j++)
            acc[i][j] = (f4v){0.f, 0.f, 0.f, 0.f};

    const int NT = K >> 5;

    auto stage_tile = [&](int buf, int kof) {
        u16* d = lds + buf * BUF + wave * 1024;
        gl2lds16(A  + gA0 + kof, d);
        gl2lds16(A  + gA1 + kof, d + 512);
        gl2lds16(Bh + gB0 + kof, d + 8192);
        gl2lds16(Bh + gB1 + kof, d + 8704);
        if (SPLITB) {
            gl2lds16(Bl + gB0 + kof, d + 16384);
            gl2lds16(Bl + gB1 + kof, d + 16896);
        }
    };

    // ---- prologue: tiles 0,1 in flight; wait tile 0 (counted); prefetch G1(0)
    stage_tile(0, 0);
    if (NT > 1) {
        stage_tile(1, 32);
        if (SPLITB) asm volatile("s_waitcnt vmcnt(6)" ::: "memory");
        else        asm volatile("s_waitcnt vmcnt(4)" ::: "memory");
    } else {
        asm volatile("s_waitcnt vmcnt(0)" ::: "memory");
    }
    SB_();
    __builtin_amdgcn_s_barrier();
    SB_();

    s8v a03[4], b01h[2], b01l[2];               // G1 (loop-carried prefetch)
    #pragma unroll
    for (int i = 0; i < 4; i++) a03[i] = *(const s8v*)&lds[offA + i * 512];
    #pragma unroll
    for (int j = 0; j < 2; j++) {
        b01h[j] = *(const s8v*)&lds[offBh + j * 512];
        if (SPLITB) b01l[j] = *(const s8v*)&lds[offBl + j * 512];
    }

    int cb = 0;
    for (int t = 0; t < NT; ++t) {
        u16* Lc = lds + cb * BUF;
        const int  nb  = (cb + 2 >= 3) ? (cb - 1) : (cb + 2);   // (cb+2)%3
        const bool st  = (t + 2) < NT;
        const int kos = (t + 2) << 5;

        // ---- G2 reads: b23 FIRST (needed by C2), then af4-7 ----
        s8v b23h[2], b23l[2], a47[4];
        #pragma unroll
        for (int j = 0; j < 2; j++) {
            b23h[j] = *(const s8v*)&Lc[offBh + (2 + j) * 512];
            if (SPLITB) b23l[j] = *(const s8v*)&Lc[offBl + (2 + j) * 512];
        }
        #pragma unroll
        for (int i = 0; i < 4; i++) a47[i] = *(const s8v*)&Lc[offA + (4 + i) * 512];

        // ---- stage tile t+2 into buffer nb (vmcnt only; lgkm untouched) ----
        if (st) stage_tile(nb, kos);

        // ---- C1: needs G1 only (G2 outstanding: 8 or 6) ----
        if (SPLITB) asm volatile("s_waitcnt lgkmcnt(8)" ::: "memory");
        else        asm volatile("s_waitcnt lgkmcnt(6)" ::: "memory");
        SB_();
        __builtin_amdgcn_s_setprio(1);
        #pragma unroll
        for (int j = 0; j < 2; j++)
            #pragma unroll
            for (int i = 0; i < 4; i++) MFMA_(acc[i][j], a03[i], b01h[j]);
        if (SPLITB) {
            #pragma unroll
            for (int j = 0; j < 2; j++)
                #pragma unroll
                for (int i = 0; i < 4; i++) MFMA_(acc[i][j], a03[i], b01l[j]);
        }

        // ---- C2: needs b23 (a47's 4 reads still outstanding) ----
        asm volatile("s_waitcnt lgkmcnt(4)" ::: "memory");
        SB_();
        #pragma unroll
        for (int j = 0; j < 2; j++)
            #pragma unroll
            for (int i = 0; i < 4; i++) MFMA_(acc[i][2 + j], a03[i], b23h[j]);
        if (SPLITB) {
            #pragma unroll
            for (int j = 0; j < 2; j++)
                #pragma unroll
                for (int i = 0; i < 4; i++) MFMA_(acc[i][2 + j], a03[i], b23l[j]);
        }

        // ---- C3: needs af4-7 ----
        asm volatile("s_waitcnt lgkmcnt(0)" ::: "memory");
        SB_();
        #pragma unroll
        for (int j = 0; j < 2; j++)
            #pragma unroll
            for (int i = 0; i < 4; i++) MFMA_(acc[4 + i][j], a47[i], b01h[j]);
        if (SPLITB) {
            #pragma unroll
            for (int j = 0; j < 2; j++)
                #pragma unroll
                for (int i = 0; i < 4; i++) MFMA_(acc[4 + i][j], a47[i], b01l[j]);
        }
        __builtin_amdgcn_s_setprio(0);

        // ---- arrival barrier for tile t+1, then prefetch G1(t+1); C4 (reg-only)
        // executes while G1(t+1)'s ds_reads drain. ----
        if (t + 1 < NT) {
            SB_();
            if (st) {
                if (SPLITB) asm volatile("s_waitcnt vmcnt(6)" ::: "memory");
                else        asm volatile("s_waitcnt vmcnt(4)" ::: "memory");
            } else {
                asm volatile("s_waitcnt vmcnt(0)" ::: "memory");
            }
            SB_();
            __builtin_amdgcn_s_barrier();
            SB_();
            const u16* Ln = lds + ((cb + 1 == 3) ? 0 : cb + 1) * BUF;
            #pragma unroll
            for (int i = 0; i < 4; i++) a03[i] = *(const s8v*)&Ln[offA + i * 512];
            #pragma unroll
            for (int j = 0; j < 2; j++) {
                b01h[j] = *(const s8v*)&Ln[offBh + j * 512];
                if (SPLITB) b01l[j] = *(const s8v*)&Ln[offBl + j * 512];
            }
            SB_();   // pin: G1(t+1) issues before C4
        }
        __builtin_amdgcn_s_setprio(1);
        #pragma unroll
        for (int j = 0; j < 2; j++)
            #pragma unroll
            for (int i = 0; i < 4; i++) MFMA_(acc[4 + i][2 + j], a47[i], b23h[j]);
        if (SPLITB) {
            #pragma unroll
            for (int j = 0; j < 2; j++)
                #pragma unroll
                for (int i = 0; i < 4; i++) MFMA_(acc[4 + i][2 + j], a47[i], b23l[j]);
        }
        __builtin_amdgcn_s_setprio(0);

        cb = (cb + 1 == 3) ? 0 : cb + 1;
    }

    // ---- epilogue ----
    const int sbase = (br > 0) ? (row0 % br) : row0;
    #pragma unroll
    for (int mf = 0; mf < 8; mf++) {
        #pragma unroll
        for (int nf = 0; nf < 4; nf++) {
            const int ng = n0 + wn * 64 + nf * 16 + l16;
            const float bv = bias ? bias[ng] : 0.f;
            float vals[4];
            #pragma unroll
            for (int rg = 0; rg < 4; rg++)
                vals[rg] = act_f<ACT>(acc[mf][nf][rg] + bv);
            if (sT) {
                u32 lo = (u32)f2bf(vals[0]) | ((u32)f2bf(vals[1]) << 16);
                u32 hi = (u32)f2bf(vals[2]) | ((u32)f2bf(vals[3]) << 16);
                uint2 pkd; pkd.x = lo; pkd.y = hi;
                long idx = (long)b * cS + (long)ng * ldcT + sbase + wm * 128 + mf * 16 + quad * 4;
                *(uint2*)&C[idx] = pkd;
            } else {
                #pragma unroll
                for (int rg = 0; rg < 4; rg++)
                    C[(long)(row0 + wm * 128 + mf * 16 + quad * 4 + rg) * N + ng] = f2bf(vals[rg]);
            }
        }
    }
}

// ---------------------------------------------------------------------------
// 128x128-tile bf16 MFMA GEMM (m97 structure), optional split-B:
//   C = act(A @ (Bh[+Bl])^T + bias) [* rowscale]
// (rowscale'd attn GEMM + N=128 composed feature-map GEMMs)
// ---------------------------------------------------------------------------
template<int ACT, int SPLITB>
__global__ __launch_bounds__(256)
void gemm128_k(const u16* __restrict__ A, const u16* __restrict__ Bh,
               const u16* __restrict__ Bl, const float* __restrict__ bias,
               const float* __restrict__ rowscale,
               u16* __restrict__ C, int M, int N, int K,
               long aS, long bS, int br, int sT, long cS, int ldcT)
{
    __shared__ u16 As [128 * 32];
    __shared__ u16 Bs [128 * 32];
    __shared__ u16 Bls[SPLITB ? 128 * 32 : 64];

    const int tid  = threadIdx.x;
    int bxs = (int)blockIdx.x, bys = (int)blockIdx.y;
    if (gridDim.z == 1) swz_bid(bxs, bys);
    const int n0   = bxs * 128;
    const int row0 = bys * 128;
    const int b    = (gridDim.z > 1) ? (int)blockIdx.z : (br > 0 ? row0 / br : 0);
    const u16* Ab  = A  + (long)b * aS;
    const u16* Bhb = Bh + (long)b * bS;
    const u16* Blb = SPLITB ? (Bl + (long)b * bS) : nullptr;

    const int lane = tid & 63, wave = tid >> 6;
    const int quad = lane >> 4, l16 = lane & 15;
    const int wm = wave >> 1, wn = wave & 1;

    const int c0 = wave * 2, c1 = wave * 2 + 1;
    const int srow = lane >> 2;          // 0..15 within chunk
    const int scol = (lane & 3) * 8;     // element col within BK=32
    const long gA0 = (long)(row0 + c0 * 16 + srow) * K + scol;
    const long gA1 = (long)(row0 + c1 * 16 + srow) * K + scol;
    const long gB0 = (long)(n0   + c0 * 16 + srow) * K + scol;
    const long gB1 = (long)(n0   + c1 * 16 + srow) * K + scol;
    u16* lA0 = &As [c0 * 512]; u16* lA1 = &As [c1 * 512];
    u16* lB0 = &Bs [c0 * 512]; u16* lB1 = &Bs [c1 * 512];
    u16* lL0 = &Bls[SPLITB ? c0 * 512 : 0];
    u16* lL1 = &Bls[SPLITB ? c1 * 512 : 0];

    f4v acc[4][4];
    #pragma unroll
    for (int i = 0; i < 4; i++)
        #pragma unroll
        for (int j = 0; j < 4; j++)
            acc[i][j] = (f4v){0.f, 0.f, 0.f, 0.f};

    for (int kt = 0; kt < K; kt += 32) {
        gl2lds16(Ab  + gA0 + kt, lA0);
        gl2lds16(Ab  + gA1 + kt, lA1);
        gl2lds16(Bhb + gB0 + kt, lB0);
        gl2lds16(Bhb + gB1 + kt, lB1);
        if (SPLITB) {
            gl2lds16(Blb + gB0 + kt, lL0);
            gl2lds16(Blb + gB1 + kt, lL1);
        }
        __syncthreads();

        s8v af[4], bh[4];
        #pragma unroll
        for (int i = 0; i < 4; i++)
            af[i] = *(const s8v*)&As[(wm * 64 + i * 16 + l16) * 32 + quad * 8];
        #pragma unroll
        for (int j = 0; j < 4; j++)
            bh[j] = *(const s8v*)&Bs[(wn * 64 + j * 16 + l16) * 32 + quad * 8];
        #pragma unroll
        for (int i = 0; i < 4; i++)
            #pragma unroll
            for (int j = 0; j < 4; j++)
                acc[i][j] = __builtin_amdgcn_mfma_f32_16x16x32_bf16(af[i], bh[j], acc[i][j], 0, 0, 0);
        if (SPLITB) {
            s8v bl[4];
            #pragma unroll
            for (int j = 0; j < 4; j++)
                bl[j] = *(const s8v*)&Bls[(wn * 64 + j * 16 + l16) * 32 + quad * 8];
            #pragma unroll
            for (int i = 0; i < 4; i++)
                #pragma unroll
                for (int j = 0; j < 4; j++)
                    acc[i][j] = __builtin_amdgcn_mfma_f32_16x16x32_bf16(af[i], bl[j], acc[i][j], 0, 0, 0);
        }
        __syncthreads();
    }

    const int sbase = (br > 0) ? (row0 % br) : row0;
    #pragma unroll
    for (int i = 0; i < 4; i++) {
        #pragma unroll
        for (int j = 0; j < 4; j++) {
            const int nl = wn * 64 + j * 16 + l16;
            const int ng = n0 + nl;
            const float bv = bias ? bias[ng] : 0.f;
            float vals[4];
            #pragma unroll
            for (int rg = 0; rg < 4; rg++) {
                const int mg = row0 + wm * 64 + i * 16 + quad * 4 + rg;
                float v = act_f<ACT>(acc[i][j][rg] + bv);
                if (rowscale) v *= rowscale[mg];
                vals[rg] = v;
            }
            if (sT) {
                u32 lo = (u32)f2bf(vals[0]) | ((u32)f2bf(vals[1]) << 16);
                u32 hi = (u32)f2bf(vals[2]) | ((u32)f2bf(vals[3]) << 16);
                uint2 pkd; pkd.x = lo; pkd.y = hi;
                long idx = (long)b * cS + (long)ng * ldcT + sbase + wm * 64 + i * 16 + quad * 4;
                *(uint2*)&C[idx] = pkd;
            } else {
                #pragma unroll
                for (int rg = 0; rg < 4; rg++) {
                    const int ml = wm * 64 + i * 16 + quad * 4 + rg;
                    C[(long)(row0 + ml) * N + ng] = f2bf(vals[rg]);
                }
            }
        }
    }
}

// ---------------------------------------------------------------------------
// kv split-K: partial[kc][b][P][D] (f32) over K-window kc*(S/KC)
// ---------------------------------------------------------------------------
__global__ __launch_bounds__(256)
void kvpart_k(const u16* __restrict__ pkT, const u16* __restrict__ vT,
              float* __restrict__ part)
{
    __shared__ u16 As[64 * 32];
    __shared__ u16 Bs[64 * 32];
    const int tid  = threadIdx.x;
    const int n0   = blockIdx.x * 64;   // D dim
    const int row0 = blockIdx.y * 64;   // P dim
    const int b    = blockIdx.z >> 3;   // KC_=8
    const int kc   = blockIdx.z & 7;
    const u16* Ab = pkT + (long)b * P_ * S_;
    const u16* Bb = vT  + (long)b * D_ * S_;

    const int lane = tid & 63, wave = tid >> 6;
    const int quad = lane >> 4, l16 = lane & 15;
    const int wm = wave >> 1, wn = wave & 1;
    const int srow = lane >> 2, scol = (lane & 3) * 8;
    const long gA = (long)(row0 + wave * 16 + srow) * S_ + scol;
    const long gB = (long)(n0   + wave * 16 + srow) * S_ + scol;
    u16* lA = &As[wave * 512];
    u16* lB = &Bs[wave * 512];

    f4v acc[2][2];
    #pragma unroll
    for (int i = 0; i < 2; i++)
        #pragma unroll
        for (int j = 0; j < 2; j++)
            acc[i][j] = (f4v){0.f, 0.f, 0.f, 0.f};

    const int k0 = kc * (S_ / KC_), k1 = k0 + S_ / KC_;
    for (int kt = k0; kt < k1; kt += 32) {
        gl2lds16(Ab + gA + kt, lA);
        gl2lds16(Bb + gB + kt, lB);
        __syncthreads();
        s8v a0 = *(const s8v*)&As[(wm * 32 + l16) * 32 + quad * 8];
        s8v a1 = *(const s8v*)&As[(wm * 32 + 16 + l16) * 32 + quad * 8];
        s8v b0 = *(const s8v*)&Bs[(wn * 32 + l16) * 32 + quad * 8];
        s8v b1 = *(const s8v*)&Bs[(wn * 32 + 16 + l16) * 32 + quad * 8];
        acc[0][0] = __builtin_amdgcn_mfma_f32_16x16x32_bf16(a0, b0, acc[0][0], 0, 0, 0);
        acc[0][1] = __builtin_amdgcn_mfma_f32_16x16x32_bf16(a0, b1, acc[0][1], 0, 0, 0);
        acc[1][0] = __builtin_amdgcn_mfma_f32_16x16x32_bf16(a1, b0, acc[1][0], 0, 0, 0);
        acc[1][1] = __builtin_amdgcn_mfma_f32_16x16x32_bf16(a1, b1, acc[1][1], 0, 0, 0);
        __syncthreads();
    }

    float* pb = part + ((long)(kc * B_ + b) * P_) * D_;
    #pragma unroll
    for (int i = 0; i < 2; i++) {
        #pragma unroll
        for (int j = 0; j < 2; j++) {
            const int ng = n0 + wn * 32 + j * 16 + l16;
            #pragma unroll
            for (int rg = 0; rg < 4; rg++) {
                const int mg = row0 + wm * 32 + i * 16 + quad * 4 + rg;
                pb[(long)mg * D_ + ng] = acc[i][j][rg];
            }
        }
    }
}

// reduce KC_ partials [P][D] -> kvT [b][D][P] bf16 (LDS 32x32 transpose)
__global__ __launch_bounds__(256)
void kvred_k(const float* __restrict__ part, u16* __restrict__ kvT)
{
    __shared__ float t[32][33];
    const int d0 = blockIdx.x * 32, p0 = blockIdx.y * 32, b = blockIdx.z;
    const int r = threadIdx.x >> 3, c4 = (threadIdx.x & 7) * 4;
    float4 s = {0.f, 0.f, 0.f, 0.f};
    #pragma unroll
    for (int kc = 0; kc < KC_; kc++) {
        const float4 v = *(const float4*)&part[(((long)(kc * B_ + b)) * P_ + p0 + r) * D_ + d0 + c4];
        s.x += v.x; s.y += v.y; s.z += v.z; s.w += v.w;
    }
    t[r][c4 + 0] = s.x; t[r][c4 + 1] = s.y; t[r][c4 + 2] = s.z; t[r][c4 + 3] = s.w;
    __syncthreads();
    u16 o[4];
    #pragma unroll
    for (int i = 0; i < 4; i++) o[i] = f2bf(t[c4 + i][r]);
    uint2 ov; ov.x = (u32)o[0] | ((u32)o[1] << 16); ov.y = (u32)o[2] | ((u32)o[3] << 16);
    *(uint2*)&kvT[(long)b * D_ * P_ + (long)(d0 + r) * P_ + p0 + c4] = ov;
}

// W [K,N] f32 -> WhT/WlT [N,K] bf16 split (w ~= hi + lo)
__global__ __launch_bounds__(256)
void tsplit_k(const float* __restrict__ W, u16* __restrict__ WhT, u16* __restrict__ WlT,
              int K, int N)
{
    __shared__ float t[32][33];
    const int n0 = blockIdx.x * 32, k0 = blockIdx.y * 32;
    const int tid = threadIdx.x;
    const int r = tid >> 3, c4 = (tid & 7) * 4;
    float4 d = *(const float4*)&W[(long)(k0 + r) * N + n0 + c4];
    t[r][c4 + 0] = d.x; t[r][c4 + 1] = d.y; t[r][c4 + 2] = d.z; t[r][c4 + 3] = d.w;
    __syncthreads();
    u16 hi[4], lo[4];
    #pragma unroll
    for (int i = 0; i < 4; i++) {
        float wv = t[c4 + i][r];
        hi[i] = f2bf(wv);
        lo[i] = f2bf(wv - bf2f(hi[i]));
    }
    uint2 hv; hv.x = (u32)hi[0] | ((u32)hi[1] << 16); hv.y = (u32)hi[2] | ((u32)hi[3] << 16);
    uint2 lv; lv.x = (u32)lo[0] | ((u32)lo[1] << 16); lv.y = (u32)lo[2] | ((u32)lo[3] << 16);
    const long oidx = (long)(n0 + r) * K + k0 + c4;
    *(uint2*)&WhT[oidx] = hv;
    *(uint2*)&WlT[oidx] = lv;
}

__global__ __launch_bounds__(256)
void embed_k(const int* __restrict__ x, const float* __restrict__ emb,
             const float* __restrict__ pos, u16* __restrict__ h)
{
    const long i8 = ((long)blockIdx.x * 256 + threadIdx.x) * 8;
    const int bs = (int)(i8 >> 9);
    const int d  = (int)(i8 & 511);
    const int tok = x[bs];
    const int sp  = bs & (S_ - 1);
    float4 e0 = *(const float4*)&emb[(long)tok * D_ + d];
    float4 e1 = *(const float4*)&emb[(long)tok * D_ + d + 4];
    float4 p0 = *(const float4*)&pos[(long)sp * D_ + d];
    float4 p1 = *(const float4*)&pos[(long)sp * D_ + d + 4];
    float4 ov; u16* ow = (u16*)&ov;
    ow[0] = f2bf(e0.x + p0.x); ow[1] = f2bf(e0.y + p0.y);
    ow[2] = f2bf(e0.z + p0.z); ow[3] = f2bf(e0.w + p0.w);
    ow[4] = f2bf(e1.x + p1.x); ow[5] = f2bf(e1.y + p1.y);
    ow[6] = f2bf(e1.z + p1.z); ow[7] = f2bf(e1.w + p1.w);
    *(float4*)&h[i8] = ov;
}

// ksum[b,p] = sum_s pkT[b,p,s]
__global__ __launch_bounds__(64)
void ksum_k(const u16* __restrict__ pkT, float* __restrict__ ks)
{
    const int bp = blockIdx.x;
    const int lane = threadIdx.x;
    const u16* row = pkT + (long)bp * S_;
    float s = 0.f;
    for (int i = lane * 8; i < S_; i += 64 * 8) {
        float4 dv = *(const float4*)&row[i];
        const u16* dw = (const u16*)&dv;
        #pragma unroll
        for (int j = 0; j < 8; j++) s += bf2f(dw[j]);
    }
    #pragma unroll
    for (int off = 32; off; off >>= 1) s += __shfl_down(s, off);
    if (lane == 0) ks[bp] = s;
}

// zinv[row] = 1 / (dot(pq[row,:], ksum[b,:]) + eps)
__global__ __launch_bounds__(256)
void zinv_k(const u16* __restrict__ pq, const float* __restrict__ ks, float* __restrict__ zi)
{
    const int row = blockIdx.x * 4 + (threadIdx.x >> 6);
    const int lane = threadIdx.x & 63;
    const u16* pr = pq + (long)row * P_;
    const float* kb = ks + (row >> 12) * P_;
    float s = bf2f(pr[lane]) * kb[lane] + bf2f(pr[lane + 64]) * kb[lane + 64];
    #pragma unroll
    for (int off = 32; off; off >>= 1) s += __shfl_down(s, off);
    if (lane == 0) zi[row] = 1.f / (s + 1e-6f);
}

// in-place LayerNorm over rows of 512 (bf16 data, f32 gains/biases)
__global__ __launch_bounds__(256)
void ln_k(u16* __restrict__ x, const float* __restrict__ g, const float* __restrict__ be)
{
    const int row = blockIdx.x * 4 + (threadIdx.x >> 6);
    const int lane = threadIdx.x & 63;
    u16* xr = x + (long)row * D_;
    float4 dv = *(const float4*)&xr[lane * 8];
    const u16* dw = (const u16*)&dv;
    float v[8], s = 0.f, s2 = 0.f;
    #pragma unroll
    for (int i = 0; i < 8; i++) { v[i] = bf2f(dw[i]); s += v[i]; s2 += v[i] * v[i]; }
    #pragma unroll
    for (int off = 32; off; off >>= 1) { s += __shfl_down(s, off); s2 += __shfl_down(s2, off); }
    s = __shfl(s, 0); s2 = __shfl(s2, 0);
    const float mu = s * (1.f / D_);
    const float var = s2 * (1.f / D_) - mu * mu;
    const float inv = rsqrtf(var + 1e-5f);
    float4 ov; u16* ow = (u16*)&ov;
    #pragma unroll
    for (int i = 0; i < 8; i++) {
        const int d = lane * 8 + i;
        ow[i] = f2bf((v[i] - mu) * inv * g[d] + be[d]);
    }
    *(float4*)&xr[lane * 8] = ov;
}

__global__ __launch_bounds__(256)
void zero_k(float* __restrict__ p, int n)
{
    const int i = blockIdx.x * 256 + threadIdx.x;
    if (i < n) p[i] = 0.f;
}

__global__ __launch_bounds__(256)
void pool_k(const u16* __restrict__ h, float* __restrict__ pooled)
{
    const int d = blockIdx.x * 256 + threadIdx.x;
    const int scnk = blockIdx.y, b = blockIdx.z;
    const u16* hb = h + (long)b * S_ * D_;
    float s = 0.f;
    for (int sr = scnk * 256; sr < scnk * 256 + 256; sr++) s += bf2f(hb[(long)sr * D_ + d]);
    atomicAdd(&pooled[b * D_ + d], s * (1.f / S_));
}

__global__ __launch_bounds__(256)
void head_k(const float* __restrict__ pooled, const float* __restrict__ Wh1, const float* __restrict__ bh1,
            const float* __restrict__ Wh2, const float* __restrict__ bh2, float* __restrict__ out)
{
    const int b = blockIdx.x, j = threadIdx.x;
    __shared__ float pl[D_];
    __shared__ float h1[DH_];
    pl[j] = pooled[b * D_ + j];
    pl[j + 256] = pooled[b * D_ + 256 + j];
    __syncthreads();
    float s = bh1[j];
    for (int d = 0; d < D_; d++) s += pl[d] * Wh1[d * DH_ + j];
    h1[j] = s > 0.f ? s : 0.f;
    __syncthreads();
    if (j < C_) {
        float o = bh2[j];
        for (int t = 0; t < DH_; t++) o += h1[t] * Wh2[t * C_ + j];
        out[b * C_ + j] = o;
    }
}

static inline void gemm256(hipStream_t st, int act, int splitb,
                           const u16* A, const u16* Bh, const u16* Bl, const float* bias,
                           u16* C, int M, int N, int K, int br, int sT, long cS, int ldcT)
{
    dim3 g(N / 256, M / 256, 1), blk(512, 1, 1);
    if (splitb) {
        switch (act) {
            case 0: gemm256_k<0,1><<<g, blk, 0, st>>>(A, Bh, Bl, bias, C, M, N, K, br, sT, cS, ldcT); break;
            case 1: gemm256_k<1,1><<<g, blk, 0, st>>>(A, Bh, Bl, bias, C, M, N, K, br, sT, cS, ldcT); break;
            case 2: gemm256_k<2,1><<<g, blk, 0, st>>>(A, Bh, Bl, bias, C, M, N, K, br, sT, cS, ldcT); break;
        }
    } else {
        switch (act) {
            case 0: gemm256_k<0,0><<<g, blk, 0, st>>>(A, Bh, Bl, bias, C, M, N, K, br, sT, cS, ldcT); break;
            case 1: gemm256_k<1,0><<<g, blk, 0, st>>>(A, Bh, Bl, bias, C, M, N, K, br, sT, cS, ldcT); break;
            case 2: gemm256_k<2,0><<<g, blk, 0, st>>>(A, Bh, Bl, bias, C, M, N, K, br, sT, cS, ldcT); break;
        }
    }
}

static inline void gemm128(hipStream_t st, int act, int splitb,
                           const u16* A, const u16* Bh, const u16* Bl, const float* bias,
                           const float* rs, u16* C, int M, int N, int K,
                           long aS, long bS, int br, int sT, long cS, int ldcT, int gz)
{
    dim3 g(N / 128, M / 128, gz), blk(256, 1, 1);
    if (splitb) {
        switch (act) {
            case 0: gemm128_k<0,1><<<g, blk, 0, st>>>(A, Bh, Bl, bias, rs, C, M, N, K, aS, bS, br, sT, cS, ldcT); break;
            case 1: gemm128_k<1,1><<<g, blk, 0, st>>>(A, Bh, Bl, bias, rs, C, M, N, K, aS, bS, br, sT, cS, ldcT); break;
            case 2: gemm128_k<2,1><<<g, blk, 0, st>>>(A, Bh, Bl, bias, rs, C, M, N, K, aS, bS, br, sT, cS, ldcT); break;
        }
    } else {
        switch (act) {
            case 0: gemm128_k<0,0><<<g, blk, 0, st>>>(A, Bh, Bl, bias, rs, C, M, N, K, aS, bS, br, sT, cS, ldcT); break;
            case 1: gemm128_k<1,0><<<g, blk, 0, st>>>(A, Bh, Bl, bias, rs, C, M, N, K, aS, bS, br, sT, cS, ldcT); break;
            case 2: gemm128_k<2,0><<<g, blk, 0, st>>>(A, Bh, Bl, bias, rs, C, M, N, K, aS, bS, br, sT, cS, ldcT); break;
        }
    }
}

extern "C" void kernel_launch(void* const* d_in, const int* in_sizes, int n_in,
                              void* d_out, int out_size, void* d_ws, size_t ws_size,
                              hipStream_t stream)
{
    const int*   x   = (const int*)d_in[0];
    const float* emb = (const float*)d_in[1];
    const float* pos = (const float*)d_in[2];
    const float* Wq  = (const float*)d_in[3];  const float* bq  = (const float*)d_in[4];
    const float* Wk  = (const float*)d_in[5];  const float* bk  = (const float*)d_in[6];
    const float* Wv  = (const float*)d_in[7];  const float* bv  = (const float*)d_in[8];
    const float* Wf  = (const float*)d_in[9];  const float* bfb = (const float*)d_in[10];
    const float* Wo  = (const float*)d_in[11]; const float* bo  = (const float*)d_in[12];
    const float* lng = (const float*)d_in[13]; const float* lnb = (const float*)d_in[14];
    const float* W1  = (const float*)d_in[15]; const float* b1  = (const float*)d_in[16];
    const float* W2  = (const float*)d_in[17]; const float* b2  = (const float*)d_in[18];
    const float* Wh1 = (const float*)d_in[19]; const float* bh1 = (const float*)d_in[20];
    const float* Wh2 = (const float*)d_in[21]; const float* bh2 = (const float*)d_in[22];
    float* out = (float*)d_out;
    (void)in_sizes; (void)n_in; (void)out_size;

    // ---- workspace layout ----
    char* w = (char*)d_ws;
    auto alloc = [&](size_t bytes) -> char* {
        char* p = w; w += (bytes + 255) & ~(size_t)255; return p;
    };
    const size_t HBYTES = (size_t)MTOT * D_ * 2;          // 33.55 MB (bf16 activations)
    u16* h    = (u16*)alloc(HBYTES);                      // hidden state / attn-out
    u16* bufA = (u16*)alloc(HBYTES);                      // pq + kvpart / W splits
    u16* bufB = (u16*)alloc(HBYTES);                      // pkT + kvT/ks/zi / ln-out
    u16* wsH  = (u16*)alloc((size_t)D_ * D_ * 2);         // weight-split scratch (<= D*D)
    u16* wsL  = (u16*)alloc((size_t)D_ * D_ * 2);
    float* fb = (float*)alloc((size_t)2 * P_ * 4);        // composed feature biases (q,k)
    float* pooled = (float*)alloc((size_t)B_ * D_ * 4);
    // MLP hidden buffer: largest row-chunk that fits ws_size (deterministic -> graph-safe)
    size_t used = (size_t)(w - (char*)d_ws);
    int mlp_chunk = MTOT;
    while (mlp_chunk > 8192 && used + (size_t)mlp_chunk * DF_ * 2 + 4096 > ws_size)
        mlp_chunk >>= 1;
    u16* bufM = (u16*)alloc((size_t)mlp_chunk * DF_ * 2);  // MLP hidden [chunk, 2048]
    u16* bufC = bufM;                                      // vT [B,D,S] overlays bufM (>= 33.55 MB)
    // overlays:
    u16*   pq     = bufA;                                        // 8.39 MB
    float* kvpart = (float*)(bufA + (size_t)MTOT * P_);          // 16.78 MB (8.39..25.2)
    float* wscr   = kvpart;                                      // wcomp partials (2 MB, same region)
    u16*   pkT    = bufB;                                        // 8.39 MB
    u16*   kvT    = bufB + (size_t)MTOT * P_;                    // 1.05 MB
    float* ks     = (float*)(kvT + (size_t)B_ * D_ * P_);        // 4 KB
    float* zi     = ks + (size_t)B_ * P_;                        // 131 KB
    u16*   attnO  = h;                                           // h dead after v-proj
    // W1/W2 split planes overlay bufA during the MLP (pq/kvpart dead by then)
    u16* W1h = bufA;
    u16* W1l = bufA + (size_t)DF_ * D_;
    u16* W2h = bufA + (size_t)2 * DF_ * D_;
    u16* W2l = bufA + (size_t)3 * DF_ * D_;

    const int WPGRID = (D_ * P_ * JC_) / 256 + 1;   // 2049 (last block = bias)

    embed_k<<<(MTOT * (long)D_) / (256 * 8), 256, 0, stream>>>(x, emb, pos, h);

    for (int l = 0; l < L_; l++) {
        const float* Wf_l = Wf + (size_t)l * D_ * P_;
        const float* bf_l = bfb + (size_t)l * P_;
        // composed q-feature: Wqf = Wq@Wf (split planes), bqf = bq@Wf+bf
        wpart_k<<<WPGRID, 256, 0, stream>>>(Wq + (size_t)l * D_ * D_, bq + (size_t)l * D_,
                                            Wf_l, bf_l, wscr, fb);
        wfin_k<<<256, 256, 0, stream>>>(wscr, wsH, wsL);
        // pq = elu1(h@Wqf + bqf) -> bufA
        gemm128(stream, 1, 1, h, wsH, wsL, fb, nullptr, pq, MTOT, P_, D_, 0, 0, 0, 0, 0, 0, 1);
        // composed k-feature
        wpart_k<<<WPGRID, 256, 0, stream>>>(Wk + (size_t)l * D_ * D_, bk + (size_t)l * D_,
                                            Wf_l, bf_l, wscr, fb + P_);
        wfin_k<<<256, 256, 0, stream>>>(wscr, wsH, wsL);
        // pkT = elu1(h@Wkf + bkf)^T per batch -> bufB
        gemm128(stream, 1, 1, h, wsH, wsL, fb + P_, nullptr, pkT, MTOT, P_, D_, 0, 0, S_, 1, (long)P_ * S_, S_, 1);
        // vT = (h@Wv+bv)^T per batch -> bufC  (h's last read)
        tsplit_k<<<dim3(D_ / 32, D_ / 32), 256, 0, stream>>>(Wv + (size_t)l * D_ * D_, wsH, wsL, D_, D_);
        gemm256(stream, 0, 1, h, wsH, wsL, bv + l * D_, bufC, MTOT, D_, D_, S_, 1, (long)D_ * S_, S_);
        // ksum, zinv
        ksum_k<<<B_ * P_, 64, 0, stream>>>(pkT, ks);
        zinv_k<<<MTOT / 4, 256, 0, stream>>>(pq, ks, zi);
        // kv split-K partials + reduce -> kvT [b][D][P]
        kvpart_k<<<dim3(D_ / 64, P_ / 64, B_ * KC_), 256, 0, stream>>>(pkT, bufC, kvpart);
        kvred_k<<<dim3(D_ / 32, P_ / 32, B_), 256, 0, stream>>>(kvpart, kvT);
        // attn = (pq @ kv) * zinv -> h region (h dead)
        gemm128(stream, 0, 0, pq, kvT, nullptr, nullptr, zi, attnO, MTOT, D_, P_, 0, (long)D_ * P_, S_, 0, 0, 0, 1);
        // o = attn@Wo+bo -> bufB (hi-plane only: LN immediately renormalizes,
        // same justification as the W1/W2 lo-drop), then LN in place
        tsplit_k<<<dim3(D_ / 32, D_ / 32), 256, 0, stream>>>(Wo + (size_t)l * D_ * D_, wsH, wsL, D_, D_);
        gemm256(stream, 0, 0, attnO, wsH, nullptr, bo + l * D_, bufB, MTOT, D_, D_, 0, 0, 0, 0);
        ln_k<<<MTOT / 4, 256, 0, stream>>>(bufB, lng + l * D_, lnb + l * D_);
        // MLP: hi-plane only (lo dropped: LN renorm + mean-pool tolerate bf16 W here)
        tsplit_k<<<dim3(DF_ / 32, D_ / 32), 256, 0, stream>>>(W1 + (size_t)l * D_ * DF_, W1h, W1l, D_, DF_);
        tsplit_k<<<dim3(D_ / 32, DF_ / 32), 256, 0, stream>>>(W2 + (size_t)l * DF_ * D_, W2h, W2l, DF_, D_);
        for (int c = 0; c < MTOT / mlp_chunk; c++) {
            const u16* aPtr = bufB + (size_t)c * mlp_chunk * D_;
            gemm256(stream, 2, 0, aPtr, W1h, nullptr, b1 + l * DF_, bufM, mlp_chunk, DF_, D_, 0, 0, 0, 0);
            gemm256(stream, 0, 0, bufM, W2h, nullptr, b2 + l * D_,  h + (size_t)c * mlp_chunk * D_, mlp_chunk, D_, DF_, 0, 0, 0, 0);
        }
    }

    zero_k<<<(B_ * D_ + 255) / 256, 256, 0, stream>>>(pooled, B_ * D_);
    pool_k<<<dim3(D_ / 256, 16, B_), 256, 0, stream>>>(h, pooled);
    head_k<<<B_, 256, 0, stream>>>(pooled, Wh1, bh1, Wh2, bh2, out);
}